// Round 8
// baseline (496.952 us; speedup 1.0000x reference)
//
#include <hip/hip_runtime.h>
#include <hip/hip_bf16.h>

// Shapes fixed by the problem:
// B=4, S=1024, D=512, H=64, DK=8, FF=2048, NQ=8. Mtok = B*S = 4096.

typedef short short8 __attribute__((ext_vector_type(8)));
typedef float floatx4 __attribute__((ext_vector_type(4)));

__device__ __forceinline__ unsigned short f2bf_bits(float f) {
  __hip_bfloat16 h = __float2bfloat16(f);
  return *reinterpret_cast<unsigned short*>(&h);
}
__device__ __forceinline__ float bfbits2f(unsigned short u) {
  union { unsigned int u; float f; } c;
  c.u = (unsigned int)u << 16;
  return c.f;
}

#define GLOBAL_LOAD_LDS16(g, l)                                               \
  __builtin_amdgcn_global_load_lds(                                           \
      (const __attribute__((address_space(1))) void*)(g),                     \
      (__attribute__((address_space(3))) void*)(l), 16, 0, 0)

// Compiler does NOT model global_load_lds's LDS write as aliasing later LDS
// reads (round-3 NaN). Explicit waits, memory clobber pins ordering.
#define WAIT_VMCNT0()   asm volatile("s_waitcnt vmcnt(0)" ::: "memory")
#define WAIT_VMCNT16()  asm volatile("s_waitcnt vmcnt(16)" ::: "memory")
#define WAIT_LGKM0()    asm volatile("s_waitcnt lgkmcnt(0)" ::: "memory")

// ---------------------------------------------------------------------------
// Manual grid barrier (round-7 lesson: hipLaunchCooperativeKernel silently
// failed to enqueue; do it ourselves). Sense-reversal generation barrier with
// AGENT-scope atomics. Correct across XCDs: __threadfence() by every thread
// (agent fence -> L2 writeback+invalidate on gfx94x+) before and after.
// Deadlock-free by construction: grid=256 blocks, 64KB LDS -> >=1 block/CU,
// all blocks co-resident on the 256-CU chip.
// ---------------------------------------------------------------------------
__device__ __forceinline__ void grid_barrier(unsigned* cnt, unsigned* gen,
                                             unsigned nb) {
  __threadfence();              // flush this XCD's L2 (all waves execute)
  __syncthreads();
  if (threadIdx.x == 0) {
    unsigned g = __hip_atomic_load(gen, __ATOMIC_RELAXED,
                                   __HIP_MEMORY_SCOPE_AGENT);
    unsigned arrived = __hip_atomic_fetch_add(cnt, 1u, __ATOMIC_ACQ_REL,
                                              __HIP_MEMORY_SCOPE_AGENT);
    if (arrived + 1 == nb) {
      __hip_atomic_store(cnt, 0u, __ATOMIC_RELAXED, __HIP_MEMORY_SCOPE_AGENT);
      __hip_atomic_fetch_add(gen, 1u, __ATOMIC_RELEASE,
                             __HIP_MEMORY_SCOPE_AGENT);
    } else {
      while (__hip_atomic_load(gen, __ATOMIC_ACQUIRE,
                               __HIP_MEMORY_SCOPE_AGENT) == g)
        __builtin_amdgcn_s_sleep(8);
    }
  }
  __syncthreads();
  __threadfence();              // invalidate stale L2 lines before new reads
}

// ---------------------------------------------------------------------------
// Single-wave GEMM core (double-buffered): acc(64x64) += A @ W^T over K.
// 4x4 of 16x16x32 MFMA, BK=64. s_waitcnt vmcnt(16): next tile's 16 DMA
// loads stay in flight across the current tile's ds_read+MFMA (2 GEMM
// waves/CU -> latency hidden by ILP). XOR chunk swizzle: phys 16B chunk p
// of row r holds logical chunk p ^ (r&7) -> conflict-free ds_read_b128.
// sh = 16384 bf16 (32 KB). Entry lgkm fence: LDS may have pending reads
// from a previous stage of the fused kernel.
// ---------------------------------------------------------------------------
__device__ __forceinline__ void gemm_core_db(
    const __hip_bfloat16* __restrict__ A,
    const __hip_bfloat16* __restrict__ W,
    int K, long m0, long n0, int lane,
    __hip_bfloat16* sh, floatx4 acc[4][4])
{
  const int srow = lane >> 3;
  const int schunk = lane & 7;
  const int gchunk = schunk ^ srow;
  const int frow = lane & 15;
  const int fk = lane >> 4;

  auto stage = [&](int kt, __hip_bfloat16* Ab, __hip_bfloat16* Bb) {
#pragma unroll
    for (int ib = 0; ib < 8; ++ib) {
      const int row = ib * 8 + srow;
      GLOBAL_LOAD_LDS16(A + (m0 + row) * K + kt + gchunk * 8, Ab + ib * 512);
      GLOBAL_LOAD_LDS16(W + (n0 + row) * K + kt + gchunk * 8, Bb + ib * 512);
    }
  };

  const int ntiles = K >> 6;
  WAIT_LGKM0();                 // prior stage's LDS reads retired
  stage(0, sh, sh + 4096);
  for (int t = 0; t < ntiles; ++t) {
    __hip_bfloat16* As = sh + (t & 1) * 8192;
    __hip_bfloat16* Bs = As + 4096;
    if (t + 1 < ntiles) {
      WAIT_LGKM0();             // other buffer's ds_reads retired before DMA
      __hip_bfloat16* An = sh + ((t + 1) & 1) * 8192;
      stage((t + 1) << 6, An, An + 4096);
      WAIT_VMCNT16();           // wait current buffer only; next stays in flight
    } else {
      WAIT_VMCNT0();
    }
    short8 af[2][4], bf[2][4];
#pragma unroll
    for (int ks = 0; ks < 2; ++ks)
#pragma unroll
      for (int i = 0; i < 4; ++i) {
        const int ar = i * 16 + frow;
        af[ks][i] = *(const short8*)(As + ar * 64 + (((ks * 4 + fk) ^ (ar & 7)) << 3));
        bf[ks][i] = *(const short8*)(Bs + ar * 64 + (((ks * 4 + fk) ^ (ar & 7)) << 3));
      }
#pragma unroll
    for (int ks = 0; ks < 2; ++ks)
#pragma unroll
      for (int i = 0; i < 4; ++i)
#pragma unroll
        for (int j = 0; j < 4; ++j)
          acc[i][j] = __builtin_amdgcn_mfma_f32_16x16x32_bf16(
              af[ks][i], bf[ks][j], acc[i][j], 0, 0, 0);
  }
}

// fp32 store epilogue, N=512, D layout row=(lane>>4)*4+reg, col=lane&15.
__device__ __forceinline__ void store_f32(
    floatx4 acc[4][4], float* __restrict__ C, const float* __restrict__ bias,
    long m0, long n0, int lane)
{
  const int col_l = lane & 15;
  const int row_l = (lane >> 4) << 2;
#pragma unroll
  for (int j = 0; j < 4; ++j) {
    const long col = n0 + j * 16 + col_l;
    const float bv = bias[col];
#pragma unroll
    for (int i = 0; i < 4; ++i)
#pragma unroll
      for (int r = 0; r < 4; ++r)
        C[(m0 + i * 16 + row_l + r) * 512 + col] = acc[i][j][r] + bv;
  }
}

__device__ __forceinline__ void cvt_one(const float* s, __hip_bfloat16* d, int n,
                                        long tid, long stride) {
  const int n4 = n >> 2;
  for (long i = tid; i < n4; i += stride) {
    float4 v = ((const float4*)s)[i];
    ushort4 u;
    u.x = f2bf_bits(v.x); u.y = f2bf_bits(v.y);
    u.z = f2bf_bits(v.z); u.w = f2bf_bits(v.w);
    ((ushort4*)d)[i] = u;
  }
}

struct MegaArgs {
  const float *x, *Wq, *bq, *Wk, *bk, *Wv, *bv, *theta, *gateA, *Wo, *bo;
  const float *ln1w, *ln1b, *W1, *b1, *W2, *b2, *phi, *gateF, *ln2w, *ln2b;
  float* out;
  __hip_bfloat16 *x_bf, *Wq_bf, *Wo_bf, *W2_bf, *W1_bf, *mix_bf, *hq_bf;
  __hip_bfloat16 *Wk_bf, *Wv_bf, *hc_bf;
  float *attn, *x1, *Qb, *Kb, *Vb, *Fb, *Fc;
  unsigned *bar_cnt, *bar_gen;
};

// ---------------------------------------------------------------------------
// Whole transformer block in ONE worker dispatch (round-6 lesson: dispatch
// overhead dominates; kernels sum ~35us). Grid 256 x 256 (4 waves), 64 KB
// LDS -> all blocks co-resident (>=1/CU). Waves 0/1 each run one R6-style
// dbuf single-wave GEMM tile per stage (512 tiles total, 2 GEMM waves/CU).
// Conditional K/V/hc/Fc GEMMs run sequentially on the same waves (uniform
// gate branches). Elementwise/LN stages: all 65K threads, grid-stride.
// ---------------------------------------------------------------------------
__global__ __launch_bounds__(256, 2) void mega(MegaArgs a)
{
  __shared__ __align__(16) __hip_bfloat16 sh[32768];   // 64 KB: 32 KB/GEMM wave
  const int tid = threadIdx.x;
  const int w = tid >> 6, lane = tid & 63;
  const unsigned nb = gridDim.x;
  const long gtid = (long)blockIdx.x * 256 + tid;
  const long gstride = (long)gridDim.x * 256;
  const float gA = *a.gateA;
  const float gF = *a.gateF;
  // GEMM tile for waves 0/1: t in [0, 512)
  const int t = blockIdx.x * 2 + w;
  const long m0 = (long)(t >> 3) * 64;      // 64 M-tiles
  const long n0 = (long)(t & 7) * 64;       // 8 N-tiles (N=512)
  __hip_bfloat16* myl = sh + w * 16384;     // 32 KB region for waves 0/1

  // ---- stage 0: fp32 -> bf16 conversions -------------------------------
  cvt_one(a.x, a.x_bf, 4096 * 512, gtid, gstride);
  cvt_one(a.Wq, a.Wq_bf, 512 * 512, gtid, gstride);
  cvt_one(a.Wo, a.Wo_bf, 512 * 512, gtid, gstride);
  cvt_one(a.W2, a.W2_bf, 512 * 2048, gtid, gstride);
  cvt_one(a.W1, a.W1_bf, 2048 * 8, gtid, gstride);
  if (gA != 1.0f) {
    cvt_one(a.Wk, a.Wk_bf, 512 * 512, gtid, gstride);
    cvt_one(a.Wv, a.Wv_bf, 512 * 512, gtid, gstride);
  }
  grid_barrier(a.bar_cnt, a.bar_gen, nb);

  // ---- stage 1: QKV GEMMs + quantum epilogue ---------------------------
  if (w < 2) {
    floatx4 acc[4][4];
#pragma unroll
    for (int i = 0; i < 4; ++i)
#pragma unroll
      for (int j = 0; j < 4; ++j) acc[i][j] = (floatx4){0.f, 0.f, 0.f, 0.f};
    gemm_core_db(a.x_bf, a.Wq_bf, 512, m0, n0, lane, myl, acc);
    const int col_l = lane & 15;
    const int row_l = (lane >> 4) << 2;
    if (gA != 1.0f) store_f32(acc, a.Qb, a.bq, m0, n0, lane);
    // quantum epilogue: LDS-transpose acc(+bias), cumprod-of-cos per head.
    float* shf = (float*)myl;   // 64x64 fp32 = 16 KB
    WAIT_LGKM0();
#pragma unroll
    for (int j = 0; j < 4; ++j) {
      const long col = n0 + j * 16 + col_l;
      const float bv = a.bq[col];
#pragma unroll
      for (int i = 0; i < 4; ++i)
#pragma unroll
        for (int r = 0; r < 4; ++r)
          shf[(i * 16 + row_l + r) * 64 + j * 16 + col_l] = acc[i][j][r] + bv;
    }
    WAIT_LGKM0();
    float th[8];
#pragma unroll
    for (int i = 0; i < 8; ++i) th[i] = a.theta[i];
#pragma unroll
    for (int t8 = 0; t8 < 8; ++t8) {
      const int gidx = t8 * 64 + lane;
      const int row = gidx >> 3;
      const int hh = gidx & 7;
      const float* src = shf + row * 64 + hh * 8;
      float c[8];
#pragma unroll
      for (int i = 0; i < 8; ++i) c[i] = __cosf(src[i] + th[i]);
      float o[8];
      float p = c[1];
#pragma unroll
      for (int i = 2; i < 8; ++i) p *= c[i];
      o[0] = p;
      float cp = c[0];
#pragma unroll
      for (int i = 1; i < 8; ++i) { cp *= c[i]; o[i] = cp; }
      union { unsigned short u16[8]; uint4 v; } pk;
#pragma unroll
      for (int i = 0; i < 8; ++i) pk.u16[i] = f2bf_bits(o[i]);
      *(uint4*)(a.mix_bf + (m0 + row) * 512 + n0 + hh * 8) = pk.v;
    }
    if (gA != 1.0f) {   // conditional K/V projections, same wave, sequential
      floatx4 acck[4][4];
#pragma unroll
      for (int i = 0; i < 4; ++i)
#pragma unroll
        for (int j = 0; j < 4; ++j) acck[i][j] = (floatx4){0.f, 0.f, 0.f, 0.f};
      gemm_core_db(a.x_bf, a.Wk_bf, 512, m0, n0, lane, myl, acck);
      store_f32(acck, a.Kb, a.bk, m0, n0, lane);
#pragma unroll
      for (int i = 0; i < 4; ++i)
#pragma unroll
        for (int j = 0; j < 4; ++j) acck[i][j] = (floatx4){0.f, 0.f, 0.f, 0.f};
      gemm_core_db(a.x_bf, a.Wv_bf, 512, m0, n0, lane, myl, acck);
      store_f32(acck, a.Vb, a.bv, m0, n0, lane);
    }
  }
  grid_barrier(a.bar_cnt, a.bar_gen, nb);

  // ---- stage 2 [cond]: classical attention + blend into mix ------------
  if (gA != 1.0f) {
    for (long idx = gtid; idx < 4 * 64 * 1024; idx += gstride) {
      const int s = (int)(idx & 1023);
      const int h = (int)((idx >> 10) & 63);
      const int b = (int)(idx >> 16);
      const long qoff = ((long)(b * 1024 + s)) * 512 + h * 8;
      float q[8];
#pragma unroll
      for (int i = 0; i < 8; ++i) q[i] = a.Qb[qoff + i] * 0.35355339059327373f;
      float m = -INFINITY, l = 0.0f, accv[8];
#pragma unroll
      for (int i = 0; i < 8; ++i) accv[i] = 0.0f;
      for (int tt = 0; tt < 1024; ++tt) {
        const long koff = ((long)(b * 1024 + tt)) * 512 + h * 8;
        const float* kr = a.Kb + koff;
        const float* vr = a.Vb + koff;
        float sc = 0.0f;
#pragma unroll
        for (int i = 0; i < 8; ++i) sc += q[i] * kr[i];
        float nm = fmaxf(m, sc);
        float corr = __expf(m - nm);
        float p = __expf(sc - nm);
        l = l * corr + p;
#pragma unroll
        for (int i = 0; i < 8; ++i) accv[i] = accv[i] * corr + p * vr[i];
        m = nm;
      }
      const float inv = 1.0f / l;
      union { unsigned short u16[8]; uint4 v; } pk;
      pk.v = *(const uint4*)(a.mix_bf + qoff);
#pragma unroll
      for (int i = 0; i < 8; ++i) {
        float quant = bfbits2f(pk.u16[i]);
        pk.u16[i] = f2bf_bits(gA * quant + (1.0f - gA) * accv[i] * inv);
      }
      *(uint4*)(a.mix_bf + qoff) = pk.v;
    }
    grid_barrier(a.bar_cnt, a.bar_gen, nb);  // uniform branch grid-wide
  }

  // ---- stage 3: attn = mix @ Wo^T + bo ---------------------------------
  if (w < 2) {
    floatx4 acc[4][4];
#pragma unroll
    for (int i = 0; i < 4; ++i)
#pragma unroll
      for (int j = 0; j < 4; ++j) acc[i][j] = (floatx4){0.f, 0.f, 0.f, 0.f};
    gemm_core_db(a.mix_bf, a.Wo_bf, 512, m0, n0, lane, myl, acc);
    store_f32(acc, a.attn, a.bo, m0, n0, lane);
  }
  grid_barrier(a.bar_cnt, a.bar_gen, nb);

  // ---- stage 4: x1 = LN(x+attn); hq = relu(qm@W1^T+b1) (+hc cond) ------
  {
    float cphi[8];
#pragma unroll
    for (int k = 0; k < 8; ++k) cphi[k] = __cosf(a.phi[k]);
    const int wg = blockIdx.x * 4 + w;     // 0..1023, 4 rows each
#pragma unroll
    for (int rr = 0; rr < 4; ++rr) {
      const long row = (long)wg * 4 + rr;
      const long base = row * 512;
      const int c0 = lane * 8;
      float4 xa = *(const float4*)(a.x + base + c0);
      float4 xb = *(const float4*)(a.x + base + c0 + 4);
      float4 ta = *(const float4*)(a.attn + base + c0);
      float4 tb = *(const float4*)(a.attn + base + c0 + 4);
      float s[8] = {xa.x + ta.x, xa.y + ta.y, xa.z + ta.z, xa.w + ta.w,
                    xb.x + tb.x, xb.y + tb.y, xb.z + tb.z, xb.w + tb.w};
      float sum = 0.f, ssq = 0.f;
#pragma unroll
      for (int i = 0; i < 8; ++i) { sum += s[i]; ssq += s[i] * s[i]; }
#pragma unroll
      for (int off = 32; off > 0; off >>= 1) {
        sum += __shfl_xor(sum, off);
        ssq += __shfl_xor(ssq, off);
      }
      const float mean = sum * (1.0f / 512.0f);
      const float var = ssq * (1.0f / 512.0f) - mean * mean;
      const float rstd = rsqrtf(fmaxf(var, 0.0f) + 1e-5f);
      float4 w0 = *(const float4*)(a.ln1w + c0);
      float4 w1 = *(const float4*)(a.ln1w + c0 + 4);
      float4 g0 = *(const float4*)(a.ln1b + c0);
      float4 g1 = *(const float4*)(a.ln1b + c0 + 4);
      const float wf[8] = {w0.x, w0.y, w0.z, w0.w, w1.x, w1.y, w1.z, w1.w};
      const float gf8[8] = {g0.x, g0.y, g0.z, g0.w, g1.x, g1.y, g1.z, g1.w};
      float o[8];
#pragma unroll
      for (int i = 0; i < 8; ++i) o[i] = (s[i] - mean) * rstd * wf[i] + gf8[i];
      *(float4*)(a.x1 + base + c0) = (float4){o[0], o[1], o[2], o[3]};
      *(float4*)(a.x1 + base + c0 + 4) = (float4){o[4], o[5], o[6], o[7]};
      // cols 0..7 live in lane 0 -> broadcast
      float q8[8], xs8[8];
#pragma unroll
      for (int k = 0; k < 8; ++k) {
        float v = __shfl(o[k], 0);
        xs8[k] = v;
        q8[k] = __cosf(v) * cphi[k];
      }
      // FFN-h: lane owns outputs nb8 = gb*512 + lane*8 (+0..7), coalesced.
#pragma unroll
      for (int gb = 0; gb < 4; ++gb) {
        const int nb8 = gb * 512 + lane * 8;
        float4 bb0 = *(const float4*)(a.b1 + nb8);
        float4 bb1 = *(const float4*)(a.b1 + nb8 + 4);
        const float bv8[8] = {bb0.x, bb0.y, bb0.z, bb0.w,
                              bb1.x, bb1.y, bb1.z, bb1.w};
        union { unsigned short u16[8]; uint4 v; } pq, px;
#pragma unroll
        for (int j = 0; j < 8; ++j) {
          uint4 wr = *(const uint4*)(a.W1_bf + (long)(nb8 + j) * 8);
          const unsigned short* pu = (const unsigned short*)&wr;
          float aq = bv8[j], ax = bv8[j];
#pragma unroll
          for (int k = 0; k < 8; ++k) {
            const float wv = bfbits2f(pu[k]);
            aq += q8[k] * wv;
            ax += xs8[k] * wv;
          }
          pq.u16[j] = f2bf_bits(fmaxf(aq, 0.0f));
          px.u16[j] = f2bf_bits(fmaxf(ax, 0.0f));
        }
        *(uint4*)(a.hq_bf + row * 2048 + nb8) = pq.v;
        if (gF != 1.0f) *(uint4*)(a.hc_bf + row * 2048 + nb8) = px.v;
      }
    }
  }
  grid_barrier(a.bar_cnt, a.bar_gen, nb);

  // ---- stage 5: Fb = hq @ W2^T + b2 (+Fc cond) -------------------------
  if (w < 2) {
    floatx4 acc[4][4];
#pragma unroll
    for (int i = 0; i < 4; ++i)
#pragma unroll
      for (int j = 0; j < 4; ++j) acc[i][j] = (floatx4){0.f, 0.f, 0.f, 0.f};
    gemm_core_db(a.hq_bf, a.W2_bf, 2048, m0, n0, lane, myl, acc);
    store_f32(acc, a.Fb, a.b2, m0, n0, lane);
    if (gF != 1.0f) {
#pragma unroll
      for (int i = 0; i < 4; ++i)
#pragma unroll
        for (int j = 0; j < 4; ++j) acc[i][j] = (floatx4){0.f, 0.f, 0.f, 0.f};
      gemm_core_db(a.hc_bf, a.W2_bf, 2048, m0, n0, lane, myl, acc);
      store_f32(acc, a.Fc, a.b2, m0, n0, lane);
    }
  }
  grid_barrier(a.bar_cnt, a.bar_gen, nb);

  // ---- stage 6: out = LN(x1 + mix(Fb, Fc; gateF)) ----------------------
  {
    const int wg = blockIdx.x * 4 + w;
#pragma unroll
    for (int rr = 0; rr < 4; ++rr) {
      const long row = (long)wg * 4 + rr;
      const long base = row * 512;
      const int c0 = lane * 8;
      float4 xa = *(const float4*)(a.x1 + base + c0);
      float4 xb = *(const float4*)(a.x1 + base + c0 + 4);
      float4 fa = *(const float4*)(a.Fb + base + c0);
      float4 fb = *(const float4*)(a.Fb + base + c0 + 4);
      float s[8];
      if (gF != 1.0f) {
        float4 ca = *(const float4*)(a.Fc + base + c0);
        float4 cb = *(const float4*)(a.Fc + base + c0 + 4);
        const float om = 1.0f - gF;
        s[0] = xa.x + gF * fa.x + om * ca.x; s[1] = xa.y + gF * fa.y + om * ca.y;
        s[2] = xa.z + gF * fa.z + om * ca.z; s[3] = xa.w + gF * fa.w + om * ca.w;
        s[4] = xb.x + gF * fb.x + om * cb.x; s[5] = xb.y + gF * fb.y + om * cb.y;
        s[6] = xb.z + gF * fb.z + om * cb.z; s[7] = xb.w + gF * fb.w + om * cb.w;
      } else {
        s[0] = xa.x + fa.x; s[1] = xa.y + fa.y; s[2] = xa.z + fa.z; s[3] = xa.w + fa.w;
        s[4] = xb.x + fb.x; s[5] = xb.y + fb.y; s[6] = xb.z + fb.z; s[7] = xb.w + fb.w;
      }
      float sum = 0.f, ssq = 0.f;
#pragma unroll
      for (int i = 0; i < 8; ++i) { sum += s[i]; ssq += s[i] * s[i]; }
#pragma unroll
      for (int off = 32; off > 0; off >>= 1) {
        sum += __shfl_xor(sum, off);
        ssq += __shfl_xor(ssq, off);
      }
      const float mean = sum * (1.0f / 512.0f);
      const float var = ssq * (1.0f / 512.0f) - mean * mean;
      const float rstd = rsqrtf(fmaxf(var, 0.0f) + 1e-5f);
      float4 w0 = *(const float4*)(a.ln2w + c0);
      float4 w1 = *(const float4*)(a.ln2w + c0 + 4);
      float4 g0 = *(const float4*)(a.ln2b + c0);
      float4 g1 = *(const float4*)(a.ln2b + c0 + 4);
      const float wf[8] = {w0.x, w0.y, w0.z, w0.w, w1.x, w1.y, w1.z, w1.w};
      const float gf8[8] = {g0.x, g0.y, g0.z, g0.w, g1.x, g1.y, g1.z, g1.w};
      float o[8];
#pragma unroll
      for (int i = 0; i < 8; ++i) o[i] = (s[i] - mean) * rstd * wf[i] + gf8[i];
      *(float4*)(a.out + base + c0) = (float4){o[0], o[1], o[2], o[3]};
      *(float4*)(a.out + base + c0 + 4) = (float4){o[4], o[5], o[6], o[7]};
    }
  }
}

// ---------------------------------------------------------------------------
extern "C" void kernel_launch(void* const* d_in, const int* in_sizes, int n_in,
                              void* d_out, int out_size, void* d_ws, size_t ws_size,
                              hipStream_t stream) {
  const size_t MB = 1024 * 1024;
  char* wsb = (char*)d_ws;

  MegaArgs a;
  a.x     = (const float*)d_in[0];
  a.Wq    = (const float*)d_in[1];
  a.bq    = (const float*)d_in[2];
  a.Wk    = (const float*)d_in[3];
  a.bk    = (const float*)d_in[4];
  a.Wv    = (const float*)d_in[5];
  a.bv    = (const float*)d_in[6];
  a.theta = (const float*)d_in[7];
  a.gateA = (const float*)d_in[8];
  a.Wo    = (const float*)d_in[9];
  a.bo    = (const float*)d_in[10];
  a.ln1w  = (const float*)d_in[11];
  a.ln1b  = (const float*)d_in[12];
  a.W1    = (const float*)d_in[13];
  a.b1    = (const float*)d_in[14];
  a.W2    = (const float*)d_in[15];
  a.b2    = (const float*)d_in[16];
  a.phi   = (const float*)d_in[17];
  a.gateF = (const float*)d_in[18];
  a.ln2w  = (const float*)d_in[19];
  a.ln2b  = (const float*)d_in[20];
  a.out   = (float*)d_out;

  a.x_bf   = (__hip_bfloat16*)(wsb + 0 * MB);              // 4 MB
  a.Wq_bf  = (__hip_bfloat16*)(wsb + 4 * MB);              // 0.5 MB
  a.Wo_bf  = (__hip_bfloat16*)(wsb + 4 * MB + 512 * 1024); // 0.5 MB
  a.W2_bf  = (__hip_bfloat16*)(wsb + 5 * MB);              // 2 MB
  a.W1_bf  = (__hip_bfloat16*)(wsb + 7 * MB);              // 32 KB
  a.mix_bf = (__hip_bfloat16*)(wsb + 8 * MB);              // 4 MB
  a.attn   = (float*)(wsb + 12 * MB);                      // 8 MB
  a.x1     = (float*)(wsb + 20 * MB);                      // 8 MB
  a.hq_bf  = (__hip_bfloat16*)(wsb + 28 * MB);             // 16 MB
  a.Fb     = (float*)(wsb + 44 * MB);                      // 8 MB
  // conditional (gate != 1) buffers
  a.Qb     = (float*)(wsb + 52 * MB);                      // 8 MB
  a.Wk_bf  = (__hip_bfloat16*)(wsb + 60 * MB);
  a.Wv_bf  = (__hip_bfloat16*)(wsb + 60 * MB + 512 * 1024);
  a.Kb     = (float*)(wsb + 61 * MB);                      // 8 MB
  a.Vb     = (float*)(wsb + 69 * MB);                      // 8 MB
  a.hc_bf  = (__hip_bfloat16*)(wsb + 77 * MB);             // 16 MB
  a.Fc     = (float*)(wsb + 93 * MB);                      // 8 MB
  a.bar_cnt = (unsigned*)(wsb + 102 * MB);
  a.bar_gen = (unsigned*)(wsb + 102 * MB + 64);

  // zero barrier state (ws is re-poisoned 0xAA before every timed call)
  hipMemsetAsync(wsb + 102 * MB, 0, 128, stream);
  mega<<<dim3(256), dim3(256), 0, stream>>>(a);
}

// Round 9
// 234.932 us; speedup vs baseline: 2.1153x; 2.1153x over previous
//
#include <hip/hip_runtime.h>
#include <hip/hip_bf16.h>

// Shapes fixed by the problem:
// B=4, S=1024, D=512, H=64, DK=8, FF=2048, NQ=8. Mtok = B*S = 4096.

typedef short short8 __attribute__((ext_vector_type(8)));
typedef float floatx4 __attribute__((ext_vector_type(4)));

__device__ __forceinline__ unsigned short f2bf_bits(float f) {
  __hip_bfloat16 h = __float2bfloat16(f);
  return *reinterpret_cast<unsigned short*>(&h);
}
__device__ __forceinline__ float bfbits2f(unsigned short u) {
  union { unsigned int u; float f; } c;
  c.u = (unsigned int)u << 16;
  return c.f;
}

#define GLOBAL_LOAD_LDS16(g, l)                                               \
  __builtin_amdgcn_global_load_lds(                                           \
      (const __attribute__((address_space(1))) void*)(g),                     \
      (__attribute__((address_space(3))) void*)(l), 16, 0, 0)

// Compiler does NOT model global_load_lds's LDS write as aliasing later LDS
// reads (round-3 NaN). Explicit waits, memory clobber pins ordering.
#define WAIT_VMCNT0()   asm volatile("s_waitcnt vmcnt(0)" ::: "memory")
#define WAIT_VMCNT16()  asm volatile("s_waitcnt vmcnt(16)" ::: "memory")
#define WAIT_LGKM0()    asm volatile("s_waitcnt lgkmcnt(0)" ::: "memory")

// ---------------------------------------------------------------------------
// Grid barrier, round-9 version. Round-8 lesson: per-thread __threadfence()
// (2048 L2 wb/inv per barrier) + ACQUIRE-spin (continuous L2 invalidation
// under working blocks) cost ~79us/barrier. This version = what cooperative
// grid.sync is: scoped atomics only. __syncthreads drains each wave's
// stores into L2; thread 0 does ONE release RMW (one buffer_wbl2/block),
// spins RELAXED (serviced at coherence point, no cache maintenance per
// poll; acquire escape valve guarantees progress), then ONE acquire load
// (one L1+L2 inv/block — covers whole block: L1 is per-CU).
// Deadlock-free: grid=256 blocks, 64KB LDS -> all blocks co-resident.
// ---------------------------------------------------------------------------
__device__ __forceinline__ void grid_barrier(unsigned* cnt, unsigned* gen,
                                             unsigned nb) {
  __syncthreads();              // all waves' stores drained to L2
  if (threadIdx.x == 0) {
    unsigned g = __hip_atomic_load(gen, __ATOMIC_RELAXED,
                                   __HIP_MEMORY_SCOPE_AGENT);
    unsigned arrived = __hip_atomic_fetch_add(cnt, 1u, __ATOMIC_RELEASE,
                                              __HIP_MEMORY_SCOPE_AGENT);
    if (arrived + 1 == nb) {
      __hip_atomic_store(cnt, 0u, __ATOMIC_RELAXED, __HIP_MEMORY_SCOPE_AGENT);
      __hip_atomic_store(gen, g + 1u, __ATOMIC_RELEASE,
                         __HIP_MEMORY_SCOPE_AGENT);
      (void)__hip_atomic_load(gen, __ATOMIC_ACQUIRE,
                              __HIP_MEMORY_SCOPE_AGENT);  // self-acquire
    } else {
      unsigned spins = 0;
      while (__hip_atomic_load(gen, __ATOMIC_RELAXED,
                               __HIP_MEMORY_SCOPE_AGENT) == g) {
        __builtin_amdgcn_s_sleep(2);
        if (++spins > (1u << 20)) {   // escape valve (never in practice)
          (void)__hip_atomic_load(gen, __ATOMIC_ACQUIRE,
                                  __HIP_MEMORY_SCOPE_AGENT);
          spins = 0;
        }
      }
      (void)__hip_atomic_load(gen, __ATOMIC_ACQUIRE,
                              __HIP_MEMORY_SCOPE_AGENT);  // inv L1+L2 once
    }
  }
  __syncthreads();
}

// ---------------------------------------------------------------------------
// Single-wave GEMM core (double-buffered): acc(64x64) += A @ W^T over K.
// 4x4 of 16x16x32 MFMA, BK=64. s_waitcnt vmcnt(16): next tile's 16 DMA
// loads stay in flight across the current tile's ds_read+MFMA (2 GEMM
// waves/CU -> latency hidden by ILP). XOR chunk swizzle: phys 16B chunk p
// of row r holds logical chunk p ^ (r&7) -> conflict-free ds_read_b128.
// sh = 16384 bf16 (32 KB). Entry lgkm fence: LDS may have pending reads
// from a previous stage of the fused kernel.
// ---------------------------------------------------------------------------
__device__ __forceinline__ void gemm_core_db(
    const __hip_bfloat16* __restrict__ A,
    const __hip_bfloat16* __restrict__ W,
    int K, long m0, long n0, int lane,
    __hip_bfloat16* sh, floatx4 acc[4][4])
{
  const int srow = lane >> 3;
  const int schunk = lane & 7;
  const int gchunk = schunk ^ srow;
  const int frow = lane & 15;
  const int fk = lane >> 4;

  auto stage = [&](int kt, __hip_bfloat16* Ab, __hip_bfloat16* Bb) {
#pragma unroll
    for (int ib = 0; ib < 8; ++ib) {
      const int row = ib * 8 + srow;
      GLOBAL_LOAD_LDS16(A + (m0 + row) * K + kt + gchunk * 8, Ab + ib * 512);
      GLOBAL_LOAD_LDS16(W + (n0 + row) * K + kt + gchunk * 8, Bb + ib * 512);
    }
  };

  const int ntiles = K >> 6;
  WAIT_LGKM0();                 // prior stage's LDS reads retired
  stage(0, sh, sh + 4096);
  for (int t = 0; t < ntiles; ++t) {
    __hip_bfloat16* As = sh + (t & 1) * 8192;
    __hip_bfloat16* Bs = As + 4096;
    if (t + 1 < ntiles) {
      WAIT_LGKM0();             // other buffer's ds_reads retired before DMA
      __hip_bfloat16* An = sh + ((t + 1) & 1) * 8192;
      stage((t + 1) << 6, An, An + 4096);
      WAIT_VMCNT16();           // wait current buffer only; next stays in flight
    } else {
      WAIT_VMCNT0();
    }
    short8 af[2][4], bf[2][4];
#pragma unroll
    for (int ks = 0; ks < 2; ++ks)
#pragma unroll
      for (int i = 0; i < 4; ++i) {
        const int ar = i * 16 + frow;
        af[ks][i] = *(const short8*)(As + ar * 64 + (((ks * 4 + fk) ^ (ar & 7)) << 3));
        bf[ks][i] = *(const short8*)(Bs + ar * 64 + (((ks * 4 + fk) ^ (ar & 7)) << 3));
      }
#pragma unroll
    for (int ks = 0; ks < 2; ++ks)
#pragma unroll
      for (int i = 0; i < 4; ++i)
#pragma unroll
        for (int j = 0; j < 4; ++j)
          acc[i][j] = __builtin_amdgcn_mfma_f32_16x16x32_bf16(
              af[ks][i], bf[ks][j], acc[i][j], 0, 0, 0);
  }
}

// fp32 store epilogue, N=512, D layout row=(lane>>4)*4+reg, col=lane&15.
__device__ __forceinline__ void store_f32(
    floatx4 acc[4][4], float* __restrict__ C, const float* __restrict__ bias,
    long m0, long n0, int lane)
{
  const int col_l = lane & 15;
  const int row_l = (lane >> 4) << 2;
#pragma unroll
  for (int j = 0; j < 4; ++j) {
    const long col = n0 + j * 16 + col_l;
    const float bv = bias[col];
#pragma unroll
    for (int i = 0; i < 4; ++i)
#pragma unroll
      for (int r = 0; r < 4; ++r)
        C[(m0 + i * 16 + row_l + r) * 512 + col] = acc[i][j][r] + bv;
  }
}

__device__ __forceinline__ void cvt_one(const float* s, __hip_bfloat16* d, int n,
                                        long tid, long stride) {
  const int n4 = n >> 2;
  for (long i = tid; i < n4; i += stride) {
    float4 v = ((const float4*)s)[i];
    ushort4 u;
    u.x = f2bf_bits(v.x); u.y = f2bf_bits(v.y);
    u.z = f2bf_bits(v.z); u.w = f2bf_bits(v.w);
    ((ushort4*)d)[i] = u;
  }
}

struct MegaArgs {
  const float *x, *Wq, *bq, *Wk, *bk, *Wv, *bv, *theta, *gateA, *Wo, *bo;
  const float *ln1w, *ln1b, *W1, *b1, *W2, *b2, *phi, *gateF, *ln2w, *ln2b;
  float* out;
  __hip_bfloat16 *x_bf, *Wq_bf, *Wo_bf, *W2_bf, *W1_bf, *mix_bf, *hq_bf;
  __hip_bfloat16 *Wk_bf, *Wv_bf, *hc_bf;
  float *attn, *x1, *Qb, *Kb, *Vb, *Fb, *Fc;
  unsigned *bar_cnt, *bar_gen;
};

// ---------------------------------------------------------------------------
// Whole transformer block in ONE worker dispatch. Grid 256 x 256 (4 waves),
// 64 KB LDS -> all blocks co-resident (>=1/CU). Waves 0/1 each run one
// R6-style dbuf single-wave GEMM tile per stage (512 tiles, 2 GEMM
// waves/CU). Conditional K/V/hc/Fc GEMMs run sequentially on the same waves
// (uniform gate branches). Elementwise/LN stages: all 65K threads.
// ---------------------------------------------------------------------------
__global__ __launch_bounds__(256, 2) void mega(MegaArgs a)
{
  __shared__ __align__(16) __hip_bfloat16 sh[32768];   // 64 KB: 32 KB/GEMM wave
  const int tid = threadIdx.x;
  const int w = tid >> 6, lane = tid & 63;
  const unsigned nb = gridDim.x;
  const long gtid = (long)blockIdx.x * 256 + tid;
  const long gstride = (long)gridDim.x * 256;
  const float gA = *a.gateA;
  const float gF = *a.gateF;
  // GEMM tile for waves 0/1: t in [0, 512)
  const int t = blockIdx.x * 2 + w;
  const long m0 = (long)(t >> 3) * 64;      // 64 M-tiles
  const long n0 = (long)(t & 7) * 64;       // 8 N-tiles (N=512)
  __hip_bfloat16* myl = sh + w * 16384;     // 32 KB region for waves 0/1

  // ---- stage 0: fp32 -> bf16 conversions -------------------------------
  cvt_one(a.x, a.x_bf, 4096 * 512, gtid, gstride);
  cvt_one(a.Wq, a.Wq_bf, 512 * 512, gtid, gstride);
  cvt_one(a.Wo, a.Wo_bf, 512 * 512, gtid, gstride);
  cvt_one(a.W2, a.W2_bf, 512 * 2048, gtid, gstride);
  cvt_one(a.W1, a.W1_bf, 2048 * 8, gtid, gstride);
  if (gA != 1.0f) {
    cvt_one(a.Wk, a.Wk_bf, 512 * 512, gtid, gstride);
    cvt_one(a.Wv, a.Wv_bf, 512 * 512, gtid, gstride);
  }
  grid_barrier(a.bar_cnt, a.bar_gen, nb);

  // ---- stage 1: QKV GEMMs + quantum epilogue ---------------------------
  if (w < 2) {
    floatx4 acc[4][4];
#pragma unroll
    for (int i = 0; i < 4; ++i)
#pragma unroll
      for (int j = 0; j < 4; ++j) acc[i][j] = (floatx4){0.f, 0.f, 0.f, 0.f};
    gemm_core_db(a.x_bf, a.Wq_bf, 512, m0, n0, lane, myl, acc);
    const int col_l = lane & 15;
    const int row_l = (lane >> 4) << 2;
    if (gA != 1.0f) store_f32(acc, a.Qb, a.bq, m0, n0, lane);
    // quantum epilogue: LDS-transpose acc(+bias), cumprod-of-cos per head.
    float* shf = (float*)myl;   // 64x64 fp32 = 16 KB
    WAIT_LGKM0();
#pragma unroll
    for (int j = 0; j < 4; ++j) {
      const long col = n0 + j * 16 + col_l;
      const float bv = a.bq[col];
#pragma unroll
      for (int i = 0; i < 4; ++i)
#pragma unroll
        for (int r = 0; r < 4; ++r)
          shf[(i * 16 + row_l + r) * 64 + j * 16 + col_l] = acc[i][j][r] + bv;
    }
    WAIT_LGKM0();
    float th[8];
#pragma unroll
    for (int i = 0; i < 8; ++i) th[i] = a.theta[i];
#pragma unroll
    for (int t8 = 0; t8 < 8; ++t8) {
      const int gidx = t8 * 64 + lane;
      const int row = gidx >> 3;
      const int hh = gidx & 7;
      const float* src = shf + row * 64 + hh * 8;
      float c[8];
#pragma unroll
      for (int i = 0; i < 8; ++i) c[i] = __cosf(src[i] + th[i]);
      float o[8];
      float p = c[1];
#pragma unroll
      for (int i = 2; i < 8; ++i) p *= c[i];
      o[0] = p;
      float cp = c[0];
#pragma unroll
      for (int i = 1; i < 8; ++i) { cp *= c[i]; o[i] = cp; }
      union { unsigned short u16[8]; uint4 v; } pk;
#pragma unroll
      for (int i = 0; i < 8; ++i) pk.u16[i] = f2bf_bits(o[i]);
      *(uint4*)(a.mix_bf + (m0 + row) * 512 + n0 + hh * 8) = pk.v;
    }
    if (gA != 1.0f) {   // conditional K/V projections, same wave, sequential
      floatx4 acck[4][4];
#pragma unroll
      for (int i = 0; i < 4; ++i)
#pragma unroll
        for (int j = 0; j < 4; ++j) acck[i][j] = (floatx4){0.f, 0.f, 0.f, 0.f};
      gemm_core_db(a.x_bf, a.Wk_bf, 512, m0, n0, lane, myl, acck);
      store_f32(acck, a.Kb, a.bk, m0, n0, lane);
#pragma unroll
      for (int i = 0; i < 4; ++i)
#pragma unroll
        for (int j = 0; j < 4; ++j) acck[i][j] = (floatx4){0.f, 0.f, 0.f, 0.f};
      gemm_core_db(a.x_bf, a.Wv_bf, 512, m0, n0, lane, myl, acck);
      store_f32(acck, a.Vb, a.bv, m0, n0, lane);
    }
  }
  grid_barrier(a.bar_cnt, a.bar_gen, nb);

  // ---- stage 2 [cond]: classical attention + blend into mix ------------
  if (gA != 1.0f) {
    for (long idx = gtid; idx < 4 * 64 * 1024; idx += gstride) {
      const int s = (int)(idx & 1023);
      const int h = (int)((idx >> 10) & 63);
      const int b = (int)(idx >> 16);
      const long qoff = ((long)(b * 1024 + s)) * 512 + h * 8;
      float q[8];
#pragma unroll
      for (int i = 0; i < 8; ++i) q[i] = a.Qb[qoff + i] * 0.35355339059327373f;
      float m = -INFINITY, l = 0.0f, accv[8];
#pragma unroll
      for (int i = 0; i < 8; ++i) accv[i] = 0.0f;
      for (int tt = 0; tt < 1024; ++tt) {
        const long koff = ((long)(b * 1024 + tt)) * 512 + h * 8;
        const float* kr = a.Kb + koff;
        const float* vr = a.Vb + koff;
        float sc = 0.0f;
#pragma unroll
        for (int i = 0; i < 8; ++i) sc += q[i] * kr[i];
        float nm = fmaxf(m, sc);
        float corr = __expf(m - nm);
        float p = __expf(sc - nm);
        l = l * corr + p;
#pragma unroll
        for (int i = 0; i < 8; ++i) accv[i] = accv[i] * corr + p * vr[i];
        m = nm;
      }
      const float inv = 1.0f / l;
      union { unsigned short u16[8]; uint4 v; } pk;
      pk.v = *(const uint4*)(a.mix_bf + qoff);
#pragma unroll
      for (int i = 0; i < 8; ++i) {
        float quant = bfbits2f(pk.u16[i]);
        pk.u16[i] = f2bf_bits(gA * quant + (1.0f - gA) * accv[i] * inv);
      }
      *(uint4*)(a.mix_bf + qoff) = pk.v;
    }
    grid_barrier(a.bar_cnt, a.bar_gen, nb);  // uniform branch grid-wide
  }

  // ---- stage 3: attn = mix @ Wo^T + bo ---------------------------------
  if (w < 2) {
    floatx4 acc[4][4];
#pragma unroll
    for (int i = 0; i < 4; ++i)
#pragma unroll
      for (int j = 0; j < 4; ++j) acc[i][j] = (floatx4){0.f, 0.f, 0.f, 0.f};
    gemm_core_db(a.mix_bf, a.Wo_bf, 512, m0, n0, lane, myl, acc);
    store_f32(acc, a.attn, a.bo, m0, n0, lane);
  }
  grid_barrier(a.bar_cnt, a.bar_gen, nb);

  // ---- stage 4: x1 = LN(x+attn); hq = relu(qm@W1^T+b1) (+hc cond) ------
  {
    float cphi[8];
#pragma unroll
    for (int k = 0; k < 8; ++k) cphi[k] = __cosf(a.phi[k]);
    const int wg = blockIdx.x * 4 + w;     // 0..1023, 4 rows each
#pragma unroll
    for (int rr = 0; rr < 4; ++rr) {
      const long row = (long)wg * 4 + rr;
      const long base = row * 512;
      const int c0 = lane * 8;
      float4 xa = *(const float4*)(a.x + base + c0);
      float4 xb = *(const float4*)(a.x + base + c0 + 4);
      float4 ta = *(const float4*)(a.attn + base + c0);
      float4 tb = *(const float4*)(a.attn + base + c0 + 4);
      float s[8] = {xa.x + ta.x, xa.y + ta.y, xa.z + ta.z, xa.w + ta.w,
                    xb.x + tb.x, xb.y + tb.y, xb.z + tb.z, xb.w + tb.w};
      float sum = 0.f, ssq = 0.f;
#pragma unroll
      for (int i = 0; i < 8; ++i) { sum += s[i]; ssq += s[i] * s[i]; }
#pragma unroll
      for (int off = 32; off > 0; off >>= 1) {
        sum += __shfl_xor(sum, off);
        ssq += __shfl_xor(ssq, off);
      }
      const float mean = sum * (1.0f / 512.0f);
      const float var = ssq * (1.0f / 512.0f) - mean * mean;
      const float rstd = rsqrtf(fmaxf(var, 0.0f) + 1e-5f);
      float4 w0 = *(const float4*)(a.ln1w + c0);
      float4 w1 = *(const float4*)(a.ln1w + c0 + 4);
      float4 g0 = *(const float4*)(a.ln1b + c0);
      float4 g1 = *(const float4*)(a.ln1b + c0 + 4);
      const float wf[8] = {w0.x, w0.y, w0.z, w0.w, w1.x, w1.y, w1.z, w1.w};
      const float gf8[8] = {g0.x, g0.y, g0.z, g0.w, g1.x, g1.y, g1.z, g1.w};
      float o[8];
#pragma unroll
      for (int i = 0; i < 8; ++i) o[i] = (s[i] - mean) * rstd * wf[i] + gf8[i];
      *(float4*)(a.x1 + base + c0) = (float4){o[0], o[1], o[2], o[3]};
      *(float4*)(a.x1 + base + c0 + 4) = (float4){o[4], o[5], o[6], o[7]};
      // cols 0..7 live in lane 0 -> broadcast
      float q8[8], xs8[8];
#pragma unroll
      for (int k = 0; k < 8; ++k) {
        float v = __shfl(o[k], 0);
        xs8[k] = v;
        q8[k] = __cosf(v) * cphi[k];
      }
      // FFN-h: lane owns outputs nb8 = gb*512 + lane*8 (+0..7), coalesced.
#pragma unroll
      for (int gb = 0; gb < 4; ++gb) {
        const int nb8 = gb * 512 + lane * 8;
        float4 bb0 = *(const float4*)(a.b1 + nb8);
        float4 bb1 = *(const float4*)(a.b1 + nb8 + 4);
        const float bv8[8] = {bb0.x, bb0.y, bb0.z, bb0.w,
                              bb1.x, bb1.y, bb1.z, bb1.w};
        union { unsigned short u16[8]; uint4 v; } pq, px;
#pragma unroll
        for (int j = 0; j < 8; ++j) {
          uint4 wr = *(const uint4*)(a.W1_bf + (long)(nb8 + j) * 8);
          const unsigned short* pu = (const unsigned short*)&wr;
          float aq = bv8[j], ax = bv8[j];
#pragma unroll
          for (int k = 0; k < 8; ++k) {
            const float wv = bfbits2f(pu[k]);
            aq += q8[k] * wv;
            ax += xs8[k] * wv;
          }
          pq.u16[j] = f2bf_bits(fmaxf(aq, 0.0f));
          px.u16[j] = f2bf_bits(fmaxf(ax, 0.0f));
        }
        *(uint4*)(a.hq_bf + row * 2048 + nb8) = pq.v;
        if (gF != 1.0f) *(uint4*)(a.hc_bf + row * 2048 + nb8) = px.v;
      }
    }
  }
  grid_barrier(a.bar_cnt, a.bar_gen, nb);

  // ---- stage 5: Fb = hq @ W2^T + b2 (+Fc cond) -------------------------
  if (w < 2) {
    floatx4 acc[4][4];
#pragma unroll
    for (int i = 0; i < 4; ++i)
#pragma unroll
      for (int j = 0; j < 4; ++j) acc[i][j] = (floatx4){0.f, 0.f, 0.f, 0.f};
    gemm_core_db(a.hq_bf, a.W2_bf, 2048, m0, n0, lane, myl, acc);
    store_f32(acc, a.Fb, a.b2, m0, n0, lane);
    if (gF != 1.0f) {
#pragma unroll
      for (int i = 0; i < 4; ++i)
#pragma unroll
        for (int j = 0; j < 4; ++j) acc[i][j] = (floatx4){0.f, 0.f, 0.f, 0.f};
      gemm_core_db(a.hc_bf, a.W2_bf, 2048, m0, n0, lane, myl, acc);
      store_f32(acc, a.Fc, a.b2, m0, n0, lane);
    }
  }
  grid_barrier(a.bar_cnt, a.bar_gen, nb);

  // ---- stage 6: out = LN(x1 + mix(Fb, Fc; gateF)) ----------------------
  {
    const int wg = blockIdx.x * 4 + w;
#pragma unroll
    for (int rr = 0; rr < 4; ++rr) {
      const long row = (long)wg * 4 + rr;
      const long base = row * 512;
      const int c0 = lane * 8;
      float4 xa = *(const float4*)(a.x1 + base + c0);
      float4 xb = *(const float4*)(a.x1 + base + c0 + 4);
      float4 fa = *(const float4*)(a.Fb + base + c0);
      float4 fb = *(const float4*)(a.Fb + base + c0 + 4);
      float s[8];
      if (gF != 1.0f) {
        float4 ca = *(const float4*)(a.Fc + base + c0);
        float4 cb = *(const float4*)(a.Fc + base + c0 + 4);
        const float om = 1.0f - gF;
        s[0] = xa.x + gF * fa.x + om * ca.x; s[1] = xa.y + gF * fa.y + om * ca.y;
        s[2] = xa.z + gF * fa.z + om * ca.z; s[3] = xa.w + gF * fa.w + om * ca.w;
        s[4] = xb.x + gF * fb.x + om * cb.x; s[5] = xb.y + gF * fb.y + om * cb.y;
        s[6] = xb.z + gF * fb.z + om * cb.z; s[7] = xb.w + gF * fb.w + om * cb.w;
      } else {
        s[0] = xa.x + fa.x; s[1] = xa.y + fa.y; s[2] = xa.z + fa.z; s[3] = xa.w + fa.w;
        s[4] = xb.x + fb.x; s[5] = xb.y + fb.y; s[6] = xb.z + fb.z; s[7] = xb.w + fb.w;
      }
      float sum = 0.f, ssq = 0.f;
#pragma unroll
      for (int i = 0; i < 8; ++i) { sum += s[i]; ssq += s[i] * s[i]; }
#pragma unroll
      for (int off = 32; off > 0; off >>= 1) {
        sum += __shfl_xor(sum, off);
        ssq += __shfl_xor(ssq, off);
      }
      const float mean = sum * (1.0f / 512.0f);
      const float var = ssq * (1.0f / 512.0f) - mean * mean;
      const float rstd = rsqrtf(fmaxf(var, 0.0f) + 1e-5f);
      float4 w0 = *(const float4*)(a.ln2w + c0);
      float4 w1 = *(const float4*)(a.ln2w + c0 + 4);
      float4 g0 = *(const float4*)(a.ln2b + c0);
      float4 g1 = *(const float4*)(a.ln2b + c0 + 4);
      const float wf[8] = {w0.x, w0.y, w0.z, w0.w, w1.x, w1.y, w1.z, w1.w};
      const float gf8[8] = {g0.x, g0.y, g0.z, g0.w, g1.x, g1.y, g1.z, g1.w};
      float o[8];
#pragma unroll
      for (int i = 0; i < 8; ++i) o[i] = (s[i] - mean) * rstd * wf[i] + gf8[i];
      *(float4*)(a.out + base + c0) = (float4){o[0], o[1], o[2], o[3]};
      *(float4*)(a.out + base + c0 + 4) = (float4){o[4], o[5], o[6], o[7]};
    }
  }
}

// ---------------------------------------------------------------------------
extern "C" void kernel_launch(void* const* d_in, const int* in_sizes, int n_in,
                              void* d_out, int out_size, void* d_ws, size_t ws_size,
                              hipStream_t stream) {
  const size_t MB = 1024 * 1024;
  char* wsb = (char*)d_ws;

  MegaArgs a;
  a.x     = (const float*)d_in[0];
  a.Wq    = (const float*)d_in[1];
  a.bq    = (const float*)d_in[2];
  a.Wk    = (const float*)d_in[3];
  a.bk    = (const float*)d_in[4];
  a.Wv    = (const float*)d_in[5];
  a.bv    = (const float*)d_in[6];
  a.theta = (const float*)d_in[7];
  a.gateA = (const float*)d_in[8];
  a.Wo    = (const float*)d_in[9];
  a.bo    = (const float*)d_in[10];
  a.ln1w  = (const float*)d_in[11];
  a.ln1b  = (const float*)d_in[12];
  a.W1    = (const float*)d_in[13];
  a.b1    = (const float*)d_in[14];
  a.W2    = (const float*)d_in[15];
  a.b2    = (const float*)d_in[16];
  a.phi   = (const float*)d_in[17];
  a.gateF = (const float*)d_in[18];
  a.ln2w  = (const float*)d_in[19];
  a.ln2b  = (const float*)d_in[20];
  a.out   = (float*)d_out;

  a.x_bf   = (__hip_bfloat16*)(wsb + 0 * MB);              // 4 MB
  a.Wq_bf  = (__hip_bfloat16*)(wsb + 4 * MB);              // 0.5 MB
  a.Wo_bf  = (__hip_bfloat16*)(wsb + 4 * MB + 512 * 1024); // 0.5 MB
  a.W2_bf  = (__hip_bfloat16*)(wsb + 5 * MB);              // 2 MB
  a.W1_bf  = (__hip_bfloat16*)(wsb + 7 * MB);              // 32 KB
  a.mix_bf = (__hip_bfloat16*)(wsb + 8 * MB);              // 4 MB
  a.attn   = (float*)(wsb + 12 * MB);                      // 8 MB
  a.x1     = (float*)(wsb + 20 * MB);                      // 8 MB
  a.hq_bf  = (__hip_bfloat16*)(wsb + 28 * MB);             // 16 MB
  a.Fb     = (float*)(wsb + 44 * MB);                      // 8 MB
  // conditional (gate != 1) buffers
  a.Qb     = (float*)(wsb + 52 * MB);                      // 8 MB
  a.Wk_bf  = (__hip_bfloat16*)(wsb + 60 * MB);
  a.Wv_bf  = (__hip_bfloat16*)(wsb + 60 * MB + 512 * 1024);
  a.Kb     = (float*)(wsb + 61 * MB);                      // 8 MB
  a.Vb     = (float*)(wsb + 69 * MB);                      // 8 MB
  a.hc_bf  = (__hip_bfloat16*)(wsb + 77 * MB);             // 16 MB
  a.Fc     = (float*)(wsb + 93 * MB);                      // 8 MB
  a.bar_cnt = (unsigned*)(wsb + 102 * MB);
  a.bar_gen = (unsigned*)(wsb + 102 * MB + 64);

  // zero barrier state (ws is re-poisoned 0xAA before every timed call)
  hipMemsetAsync(wsb + 102 * MB, 0, 128, stream);
  mega<<<dim3(256), dim3(256), 0, stream>>>(a);
}

// Round 10
// 223.232 us; speedup vs baseline: 2.2262x; 1.0524x over previous
//
#include <hip/hip_runtime.h>
#include <hip/hip_bf16.h>

// Shapes fixed by the problem:
// B=4, S=1024, D=512, H=64, DK=8, FF=2048, NQ=8. Mtok = B*S = 4096.

typedef short short8 __attribute__((ext_vector_type(8)));
typedef float floatx4 __attribute__((ext_vector_type(4)));

__device__ __forceinline__ unsigned short f2bf_bits(float f) {
  __hip_bfloat16 h = __float2bfloat16(f);
  return *reinterpret_cast<unsigned short*>(&h);
}
__device__ __forceinline__ float bfbits2f(unsigned short u) {
  union { unsigned int u; float f; } c;
  c.u = (unsigned int)u << 16;
  return c.f;
}

#define GLOBAL_LOAD_LDS16(g, l)                                               \
  __builtin_amdgcn_global_load_lds(                                           \
      (const __attribute__((address_space(1))) void*)(g),                     \
      (__attribute__((address_space(3))) void*)(l), 16, 0, 0)

// Compiler does NOT model global_load_lds's LDS write as aliasing later LDS
// reads (round-3 NaN). Explicit waits, memory clobber pins ordering.
#define WAIT_VMCNT0()   asm volatile("s_waitcnt vmcnt(0)" ::: "memory")
#define WAIT_VMCNT16()  asm volatile("s_waitcnt vmcnt(16)" ::: "memory")
#define WAIT_LGKM0()    asm volatile("s_waitcnt lgkmcnt(0)" ::: "memory")

#define ATOM_LD_RLX(p)  __hip_atomic_load((p), __ATOMIC_RELAXED, __HIP_MEMORY_SCOPE_AGENT)
#define ATOM_LD_ACQ(p)  __hip_atomic_load((p), __ATOMIC_ACQUIRE, __HIP_MEMORY_SCOPE_AGENT)
#define ATOM_ST_RLX(p,v) __hip_atomic_store((p), (v), __ATOMIC_RELAXED, __HIP_MEMORY_SCOPE_AGENT)
#define ATOM_ST_REL(p,v) __hip_atomic_store((p), (v), __ATOMIC_RELEASE, __HIP_MEMORY_SCOPE_AGENT)
#define ATOM_ADD_REL(p,v) __hip_atomic_fetch_add((p), (v), __ATOMIC_RELEASE, __HIP_MEMORY_SCOPE_AGENT)
#define ATOM_ADD_AR(p,v)  __hip_atomic_fetch_add((p), (v), __ATOMIC_ACQ_REL, __HIP_MEMORY_SCOPE_AGENT)

// ---------------------------------------------------------------------------
// Two-level grid barrier (round-9 lesson: 256 release-RMWs on ONE cacheline
// serialize at the coherence point). Level 1: 8 group counters on separate
// 128B lines (32 RMWs each, in parallel). Level 2: group leaders (8) hit one
// global counter; last leader resets + bumps gen. Spin RELAXED (no cache
// maintenance per poll), one ACQUIRE at exit (L1+L2 inv, once per block).
// Deadlock-free: 256 blocks, 96KB LDS -> all co-resident (1/CU).
// ---------------------------------------------------------------------------
__device__ __forceinline__ void grid_barrier(unsigned* cnt8, unsigned* gcnt,
                                             unsigned* gen) {
  __syncthreads();              // all waves' stores drained to L2
  if (threadIdx.x == 0) {
    const unsigned g = ATOM_LD_RLX(gen);
    unsigned* my = cnt8 + (blockIdx.x & 7) * 32;   // 128B-spaced lines
    unsigned arrived = ATOM_ADD_REL(my, 1u);       // release: wbl2 once/block
    if (arrived + 1 == 32) {
      unsigned gl = ATOM_ADD_AR(gcnt, 1u);
      if (gl + 1 == 8) {
#pragma unroll
        for (int i = 0; i < 8; ++i) ATOM_ST_RLX(cnt8 + i * 32, 0u);
        ATOM_ST_RLX(gcnt, 0u);
        ATOM_ST_REL(gen, g + 1u);
      }
    }
    unsigned spins = 0;
    while (ATOM_LD_RLX(gen) == g) {
      __builtin_amdgcn_s_sleep(2);
      if (++spins > (1u << 20)) { (void)ATOM_LD_ACQ(gen); spins = 0; }
    }
    (void)ATOM_LD_ACQ(gen);     // inv L1+L2 once; fresh reads next stage
  }
  __syncthreads();
}

// ---------------------------------------------------------------------------
// GEMM cores: acc(64x64) += A[m0:,kt..kt+Klen) @ W[n0:,...]^T, row stride ld.
// db = double-buffered (32 KB region), sb = single-buffered (16 KB region).
// XOR chunk swizzle -> conflict-free ds_read_b128 (see earlier rounds).
// ---------------------------------------------------------------------------
__device__ __forceinline__ void gemm_core_db(
    const __hip_bfloat16* __restrict__ A, const __hip_bfloat16* __restrict__ W,
    int ld, int Klen, long m0, long n0, int lane,
    __hip_bfloat16* sh, floatx4 acc[4][4])
{
  const int srow = lane >> 3;
  const int gchunk = (lane & 7) ^ srow;
  const int frow = lane & 15;
  const int fk = lane >> 4;
  auto stage = [&](int kt, __hip_bfloat16* Ab, __hip_bfloat16* Bb) {
#pragma unroll
    for (int ib = 0; ib < 8; ++ib) {
      const int row = ib * 8 + srow;
      GLOBAL_LOAD_LDS16(A + (m0 + row) * ld + kt + gchunk * 8, Ab + ib * 512);
      GLOBAL_LOAD_LDS16(W + (n0 + row) * ld + kt + gchunk * 8, Bb + ib * 512);
    }
  };
  const int ntiles = Klen >> 6;
  WAIT_LGKM0();                 // prior stage's LDS reads retired
  stage(0, sh, sh + 4096);
  for (int t = 0; t < ntiles; ++t) {
    __hip_bfloat16* As = sh + (t & 1) * 8192;
    __hip_bfloat16* Bs = As + 4096;
    if (t + 1 < ntiles) {
      WAIT_LGKM0();
      __hip_bfloat16* An = sh + ((t + 1) & 1) * 8192;
      stage((t + 1) << 6, An, An + 4096);
      WAIT_VMCNT16();           // current buffer only; next stays in flight
    } else {
      WAIT_VMCNT0();
    }
    short8 af[2][4], bf[2][4];
#pragma unroll
    for (int ks = 0; ks < 2; ++ks)
#pragma unroll
      for (int i = 0; i < 4; ++i) {
        const int ar = i * 16 + frow;
        af[ks][i] = *(const short8*)(As + ar * 64 + (((ks * 4 + fk) ^ (ar & 7)) << 3));
        bf[ks][i] = *(const short8*)(Bs + ar * 64 + (((ks * 4 + fk) ^ (ar & 7)) << 3));
      }
#pragma unroll
    for (int ks = 0; ks < 2; ++ks)
#pragma unroll
      for (int i = 0; i < 4; ++i)
#pragma unroll
        for (int j = 0; j < 4; ++j)
          acc[i][j] = __builtin_amdgcn_mfma_f32_16x16x32_bf16(
              af[ks][i], bf[ks][j], acc[i][j], 0, 0, 0);
  }
}

__device__ __forceinline__ void gemm_core_sb(
    const __hip_bfloat16* __restrict__ A, const __hip_bfloat16* __restrict__ W,
    int ld, int Klen, long m0, long n0, int lane,
    __hip_bfloat16* sh, floatx4 acc[4][4])
{
  const int srow = lane >> 3;
  const int gchunk = (lane & 7) ^ srow;
  const int frow = lane & 15;
  const int fk = lane >> 4;
  const int ntiles = Klen >> 6;
  for (int t = 0; t < ntiles; ++t) {
    WAIT_LGKM0();
#pragma unroll
    for (int ib = 0; ib < 8; ++ib) {
      const int row = ib * 8 + srow;
      GLOBAL_LOAD_LDS16(A + (m0 + row) * ld + (t << 6) + gchunk * 8, sh + ib * 512);
      GLOBAL_LOAD_LDS16(W + (n0 + row) * ld + (t << 6) + gchunk * 8, sh + 4096 + ib * 512);
    }
    WAIT_VMCNT0();
    short8 af[2][4], bf[2][4];
#pragma unroll
    for (int ks = 0; ks < 2; ++ks)
#pragma unroll
      for (int i = 0; i < 4; ++i) {
        const int ar = i * 16 + frow;
        af[ks][i] = *(const short8*)(sh + ar * 64 + (((ks * 4 + fk) ^ (ar & 7)) << 3));
        bf[ks][i] = *(const short8*)(sh + 4096 + ar * 64 + (((ks * 4 + fk) ^ (ar & 7)) << 3));
      }
#pragma unroll
    for (int ks = 0; ks < 2; ++ks)
#pragma unroll
      for (int i = 0; i < 4; ++i)
#pragma unroll
        for (int j = 0; j < 4; ++j)
          acc[i][j] = __builtin_amdgcn_mfma_f32_16x16x32_bf16(
              af[ks][i], bf[ks][j], acc[i][j], 0, 0, 0);
  }
}

// fp32 store epilogue, N=512, D layout row=(lane>>4)*4+reg, col=lane&15.
__device__ __forceinline__ void store_f32(
    floatx4 acc[4][4], float* __restrict__ C, const float* __restrict__ bias,
    long m0, long n0, int lane)
{
  const int col_l = lane & 15;
  const int row_l = (lane >> 4) << 2;
#pragma unroll
  for (int j = 0; j < 4; ++j) {
    const long col = n0 + j * 16 + col_l;
    const float bv = bias[col];
#pragma unroll
    for (int i = 0; i < 4; ++i)
#pragma unroll
      for (int r = 0; r < 4; ++r)
        C[(m0 + i * 16 + row_l + r) * 512 + col] = acc[i][j][r] + bv;
  }
}

__device__ __forceinline__ void cvt_one(const float* s, __hip_bfloat16* d, int n,
                                        long tid, long stride) {
  const int n4 = n >> 2;
  for (long i = tid; i < n4; i += stride) {
    float4 v = ((const float4*)s)[i];
    ushort4 u;
    u.x = f2bf_bits(v.x); u.y = f2bf_bits(v.y);
    u.z = f2bf_bits(v.z); u.w = f2bf_bits(v.w);
    ((ushort4*)d)[i] = u;
  }
}

struct MegaArgs {
  const float *x, *Wq, *bq, *Wk, *bk, *Wv, *bv, *theta, *gateA, *Wo, *bo;
  const float *ln1w, *ln1b, *W1, *b1, *W2, *b2, *phi, *gateF, *ln2w, *ln2b;
  float* out;
  __hip_bfloat16 *x_bf, *Wq_bf, *Wo_bf, *W2_bf, *mix_bf, *hq_bf;
  __hip_bfloat16 *Wk_bf, *Wv_bf, *hc_bf;
  float *attn, *x1, *Qb, *Kb, *Vb, *Fb, *Fc;
  unsigned *bar_cnt8, *bar_gcnt, *bar_gen;
};

// ---------------------------------------------------------------------------
// One dispatch, persistent grid 256 x 256, 96 KB LDS (1 block/CU, all
// co-resident). GEMM: K-split wave pairs — wave w (0/1) computes lower
// half-K of its tile with the 32KB dbuf core; wave w+2 computes upper
// half-K with a 16KB sbuf core; partials merged through LDS. Tile map is
// XCD-local (xcd = blockIdx&7 owns m-rows [xcd*8*64, ...)): each XCD
// fetches only its 1/8 A-slice (round-9 lesson: the old map made every XCD
// read the whole operand -> 128MB logical traffic).
// LDS: wave0 dbuf [0,32K) wave1 dbuf [32K,64K) wave2 sb [64K,80K)
//      wave3 sb [80K,96K); sb regions double as acc-exchange buffers.
// ---------------------------------------------------------------------------
__global__ __launch_bounds__(256, 1) void mega(MegaArgs a)
{
  __shared__ __align__(16) __hip_bfloat16 sh[49152];   // 96 KB
  const int tid = threadIdx.x;
  const int w = tid >> 6, lane = tid & 63;
  const long gtid = (long)blockIdx.x * 256 + tid;
  const long gstride = (long)gridDim.x * 256;
  const float gA = *a.gateA;
  const float gF = *a.gateF;
  // XCD-local tile map: 2 tiles per block (pair p = w&1), 64 tiles per XCD.
  const int xcd = blockIdx.x & 7;
  const int local = blockIdx.x >> 3;        // 0..31
  const int p = w & 1;
  const int tl = local * 2 + p;             // 0..63
  const long m0 = (long)(xcd * 8 + (tl >> 3)) * 64;
  const long n0 = (long)(tl & 7) * 64;
  __hip_bfloat16* dbl = sh + p * 16384;            // 32KB dbuf (waves 0/1)
  __hip_bfloat16* sbl = sh + 32768 + p * 8192;     // 16KB sbuf (waves 2/3)
  // LN-stage row block, XCD-local: rows [xcd*512 + local*16, +16)
  const long lnrow0 = (long)xcd * 512 + local * 16 + w * 4;

  // K-split GEMM of one 64x64 tile; result valid in acc for waves 0/1.
  auto gemm_pair = [&](const __hip_bfloat16* A, const __hip_bfloat16* W,
                       int K, floatx4 acc[4][4]) {
    const int half = K >> 1;
    if (w < 2)
      gemm_core_db(A, W, K, half, m0, n0, lane, dbl, acc);
    else
      gemm_core_sb(A + half, W + half, K, half, m0, n0, lane, sbl, acc);
    const int col_l = lane & 15;
    const int row_l = (lane >> 4) << 2;
    WAIT_LGKM0();               // own ds_reads retired before region reuse
    if (w >= 2) {
      float* xf = (float*)sbl;  // 16 KB = 64x64 fp32
#pragma unroll
      for (int j = 0; j < 4; ++j)
#pragma unroll
        for (int i = 0; i < 4; ++i)
#pragma unroll
          for (int r = 0; r < 4; ++r)
            xf[(i * 16 + row_l + r) * 64 + j * 16 + col_l] = acc[i][j][r];
    }
    __syncthreads();
    if (w < 2) {
      const float* xf = (const float*)(sh + 32768 + p * 8192);
#pragma unroll
      for (int j = 0; j < 4; ++j)
#pragma unroll
        for (int i = 0; i < 4; ++i)
#pragma unroll
          for (int r = 0; r < 4; ++r)
            acc[i][j][r] += xf[(i * 16 + row_l + r) * 64 + j * 16 + col_l];
    }
    __syncthreads();            // release exchange region for next pair
  };

  // ---- stage 0: fp32 -> bf16 conversions -------------------------------
  cvt_one(a.x, a.x_bf, 4096 * 512, gtid, gstride);
  cvt_one(a.Wq, a.Wq_bf, 512 * 512, gtid, gstride);
  cvt_one(a.Wo, a.Wo_bf, 512 * 512, gtid, gstride);
  cvt_one(a.W2, a.W2_bf, 512 * 2048, gtid, gstride);
  if (gA != 1.0f) {
    cvt_one(a.Wk, a.Wk_bf, 512 * 512, gtid, gstride);
    cvt_one(a.Wv, a.Wv_bf, 512 * 512, gtid, gstride);
  }
  grid_barrier(a.bar_cnt8, a.bar_gcnt, a.bar_gen);

  // ---- stage 1: QKV GEMMs + quantum epilogue ---------------------------
  {
    floatx4 acc[4][4];
#pragma unroll
    for (int i = 0; i < 4; ++i)
#pragma unroll
      for (int j = 0; j < 4; ++j) acc[i][j] = (floatx4){0.f, 0.f, 0.f, 0.f};
    gemm_pair(a.x_bf, a.Wq_bf, 512, acc);
    if (w < 2) {
      const int col_l = lane & 15;
      const int row_l = (lane >> 4) << 2;
      if (gA != 1.0f) store_f32(acc, a.Qb, a.bq, m0, n0, lane);
      // quantum epilogue in own dbuf region (16 KB fp32)
      float* shf = (float*)dbl;
      WAIT_LGKM0();
#pragma unroll
      for (int j = 0; j < 4; ++j) {
        const long col = n0 + j * 16 + col_l;
        const float bv = a.bq[col];
#pragma unroll
        for (int i = 0; i < 4; ++i)
#pragma unroll
          for (int r = 0; r < 4; ++r)
            shf[(i * 16 + row_l + r) * 64 + j * 16 + col_l] = acc[i][j][r] + bv;
      }
      WAIT_LGKM0();
      float th[8];
#pragma unroll
      for (int i = 0; i < 8; ++i) th[i] = a.theta[i];
#pragma unroll
      for (int t8 = 0; t8 < 8; ++t8) {
        const int gidx = t8 * 64 + lane;
        const int row = gidx >> 3;
        const int hh = gidx & 7;
        const float* src = shf + row * 64 + hh * 8;
        float c[8];
#pragma unroll
        for (int i = 0; i < 8; ++i) c[i] = __cosf(src[i] + th[i]);
        float o[8];
        float pr = c[1];
#pragma unroll
        for (int i = 2; i < 8; ++i) pr *= c[i];
        o[0] = pr;
        float cp = c[0];
#pragma unroll
        for (int i = 1; i < 8; ++i) { cp *= c[i]; o[i] = cp; }
        union { unsigned short u16[8]; uint4 v; } pk;
#pragma unroll
        for (int i = 0; i < 8; ++i) pk.u16[i] = f2bf_bits(o[i]);
        *(uint4*)(a.mix_bf + (m0 + row) * 512 + n0 + hh * 8) = pk.v;
      }
    }
    if (gA != 1.0f) {
      floatx4 acck[4][4];
#pragma unroll
      for (int i = 0; i < 4; ++i)
#pragma unroll
        for (int j = 0; j < 4; ++j) acck[i][j] = (floatx4){0.f, 0.f, 0.f, 0.f};
      gemm_pair(a.x_bf, a.Wk_bf, 512, acck);
      if (w < 2) store_f32(acck, a.Kb, a.bk, m0, n0, lane);
#pragma unroll
      for (int i = 0; i < 4; ++i)
#pragma unroll
        for (int j = 0; j < 4; ++j) acck[i][j] = (floatx4){0.f, 0.f, 0.f, 0.f};
      gemm_pair(a.x_bf, a.Wv_bf, 512, acck);
      if (w < 2) store_f32(acck, a.Vb, a.bv, m0, n0, lane);
    }
  }
  grid_barrier(a.bar_cnt8, a.bar_gcnt, a.bar_gen);

  // ---- stage 2 [cond]: classical attention + blend into mix ------------
  if (gA != 1.0f) {
    for (long idx = gtid; idx < 4 * 64 * 1024; idx += gstride) {
      const int s = (int)(idx & 1023);
      const int h = (int)((idx >> 10) & 63);
      const int b = (int)(idx >> 16);
      const long qoff = ((long)(b * 1024 + s)) * 512 + h * 8;
      float q[8];
#pragma unroll
      for (int i = 0; i < 8; ++i) q[i] = a.Qb[qoff + i] * 0.35355339059327373f;
      float m = -INFINITY, l = 0.0f, accv[8];
#pragma unroll
      for (int i = 0; i < 8; ++i) accv[i] = 0.0f;
      for (int tt = 0; tt < 1024; ++tt) {
        const long koff = ((long)(b * 1024 + tt)) * 512 + h * 8;
        const float* kr = a.Kb + koff;
        const float* vr = a.Vb + koff;
        float sc = 0.0f;
#pragma unroll
        for (int i = 0; i < 8; ++i) sc += q[i] * kr[i];
        float nm = fmaxf(m, sc);
        float corr = __expf(m - nm);
        float pe = __expf(sc - nm);
        l = l * corr + pe;
#pragma unroll
        for (int i = 0; i < 8; ++i) accv[i] = accv[i] * corr + pe * vr[i];
        m = nm;
      }
      const float inv = 1.0f / l;
      union { unsigned short u16[8]; uint4 v; } pk;
      pk.v = *(const uint4*)(a.mix_bf + qoff);
#pragma unroll
      for (int i = 0; i < 8; ++i) {
        float quant = bfbits2f(pk.u16[i]);
        pk.u16[i] = f2bf_bits(gA * quant + (1.0f - gA) * accv[i] * inv);
      }
      *(uint4*)(a.mix_bf + qoff) = pk.v;
    }
    grid_barrier(a.bar_cnt8, a.bar_gcnt, a.bar_gen);  // uniform branch
  }

  // ---- stage 3: attn = mix @ Wo^T + bo ---------------------------------
  {
    floatx4 acc[4][4];
#pragma unroll
    for (int i = 0; i < 4; ++i)
#pragma unroll
      for (int j = 0; j < 4; ++j) acc[i][j] = (floatx4){0.f, 0.f, 0.f, 0.f};
    gemm_pair(a.mix_bf, a.Wo_bf, 512, acc);
    if (w < 2) store_f32(acc, a.attn, a.bo, m0, n0, lane);
  }
  grid_barrier(a.bar_cnt8, a.bar_gcnt, a.bar_gen);

  // ---- stage 4: x1 = LN(x+attn); hq = relu(qm@W1^T+b1) (+hc cond) ------
  {
    float cphi[8];
#pragma unroll
    for (int k = 0; k < 8; ++k) cphi[k] = __cosf(a.phi[k]);
#pragma unroll
    for (int rr = 0; rr < 4; ++rr) {
      const long row = lnrow0 + rr;
      const long base = row * 512;
      const int c0 = lane * 8;
      float4 xa = *(const float4*)(a.x + base + c0);
      float4 xb = *(const float4*)(a.x + base + c0 + 4);
      float4 ta = *(const float4*)(a.attn + base + c0);
      float4 tb = *(const float4*)(a.attn + base + c0 + 4);
      float s[8] = {xa.x + ta.x, xa.y + ta.y, xa.z + ta.z, xa.w + ta.w,
                    xb.x + tb.x, xb.y + tb.y, xb.z + tb.z, xb.w + tb.w};
      float sum = 0.f, ssq = 0.f;
#pragma unroll
      for (int i = 0; i < 8; ++i) { sum += s[i]; ssq += s[i] * s[i]; }
#pragma unroll
      for (int off = 32; off > 0; off >>= 1) {
        sum += __shfl_xor(sum, off);
        ssq += __shfl_xor(ssq, off);
      }
      const float mean = sum * (1.0f / 512.0f);
      const float var = ssq * (1.0f / 512.0f) - mean * mean;
      const float rstd = rsqrtf(fmaxf(var, 0.0f) + 1e-5f);
      float4 w0 = *(const float4*)(a.ln1w + c0);
      float4 w1 = *(const float4*)(a.ln1w + c0 + 4);
      float4 g0 = *(const float4*)(a.ln1b + c0);
      float4 g1 = *(const float4*)(a.ln1b + c0 + 4);
      const float wf[8] = {w0.x, w0.y, w0.z, w0.w, w1.x, w1.y, w1.z, w1.w};
      const float gf8[8] = {g0.x, g0.y, g0.z, g0.w, g1.x, g1.y, g1.z, g1.w};
      float o[8];
#pragma unroll
      for (int i = 0; i < 8; ++i) o[i] = (s[i] - mean) * rstd * wf[i] + gf8[i];
      *(float4*)(a.x1 + base + c0) = (float4){o[0], o[1], o[2], o[3]};
      *(float4*)(a.x1 + base + c0 + 4) = (float4){o[4], o[5], o[6], o[7]};
      float q8[8], xs8[8];
#pragma unroll
      for (int k = 0; k < 8; ++k) {
        float v = __shfl(o[k], 0);     // cols 0..7 live in lane 0
        xs8[k] = v;
        q8[k] = __cosf(v) * cphi[k];
      }
#pragma unroll
      for (int gb = 0; gb < 4; ++gb) {
        const int nb8 = gb * 512 + lane * 8;
        float4 bb0 = *(const float4*)(a.b1 + nb8);
        float4 bb1 = *(const float4*)(a.b1 + nb8 + 4);
        const float bv8[8] = {bb0.x, bb0.y, bb0.z, bb0.w,
                              bb1.x, bb1.y, bb1.z, bb1.w};
        union { unsigned short u16[8]; uint4 v; } pq, px;
#pragma unroll
        for (int j = 0; j < 8; ++j) {
          float4 w1a = *(const float4*)(a.W1 + (long)(nb8 + j) * 8);
          float4 w1b = *(const float4*)(a.W1 + (long)(nb8 + j) * 8 + 4);
          const float wv[8] = {w1a.x, w1a.y, w1a.z, w1a.w,
                               w1b.x, w1b.y, w1b.z, w1b.w};
          float aq = bv8[j], ax = bv8[j];
#pragma unroll
          for (int k = 0; k < 8; ++k) {
            aq += q8[k] * wv[k];
            ax += xs8[k] * wv[k];
          }
          pq.u16[j] = f2bf_bits(fmaxf(aq, 0.0f));
          px.u16[j] = f2bf_bits(fmaxf(ax, 0.0f));
        }
        *(uint4*)(a.hq_bf + row * 2048 + nb8) = pq.v;
        if (gF != 1.0f) *(uint4*)(a.hc_bf + row * 2048 + nb8) = px.v;
      }
    }
  }
  grid_barrier(a.bar_cnt8, a.bar_gcnt, a.bar_gen);

  // ---- stage 5: Fb = hq @ W2^T + b2 (+Fc cond) -------------------------
  {
    floatx4 acc[4][4];
#pragma unroll
    for (int i = 0; i < 4; ++i)
#pragma unroll
      for (int j = 0; j < 4; ++j) acc[i][j] = (floatx4){0.f, 0.f, 0.f, 0.f};
    gemm_pair(a.hq_bf, a.W2_bf, 2048, acc);
    if (w < 2) store_f32(acc, a.Fb, a.b2, m0, n0, lane);
    if (gF != 1.0f) {
#pragma unroll
      for (int i = 0; i < 4; ++i)
#pragma unroll
        for (int j = 0; j < 4; ++j) acc[i][j] = (floatx4){0.f, 0.f, 0.f, 0.f};
      gemm_pair(a.hc_bf, a.W2_bf, 2048, acc);
      if (w < 2) store_f32(acc, a.Fc, a.b2, m0, n0, lane);
    }
  }
  grid_barrier(a.bar_cnt8, a.bar_gcnt, a.bar_gen);

  // ---- stage 6: out = LN(x1 + mix(Fb, Fc; gateF)) ----------------------
  {
#pragma unroll
    for (int rr = 0; rr < 4; ++rr) {
      const long row = lnrow0 + rr;
      const long base = row * 512;
      const int c0 = lane * 8;
      float4 xa = *(const float4*)(a.x1 + base + c0);
      float4 xb = *(const float4*)(a.x1 + base + c0 + 4);
      float4 fa = *(const float4*)(a.Fb + base + c0);
      float4 fb = *(const float4*)(a.Fb + base + c0 + 4);
      float s[8];
      if (gF != 1.0f) {
        float4 ca = *(const float4*)(a.Fc + base + c0);
        float4 cb = *(const float4*)(a.Fc + base + c0 + 4);
        const float om = 1.0f - gF;
        s[0] = xa.x + gF * fa.x + om * ca.x; s[1] = xa.y + gF * fa.y + om * ca.y;
        s[2] = xa.z + gF * fa.z + om * ca.z; s[3] = xa.w + gF * fa.w + om * ca.w;
        s[4] = xb.x + gF * fb.x + om * cb.x; s[5] = xb.y + gF * fb.y + om * cb.y;
        s[6] = xb.z + gF * fb.z + om * cb.z; s[7] = xb.w + gF * fb.w + om * cb.w;
      } else {
        s[0] = xa.x + fa.x; s[1] = xa.y + fa.y; s[2] = xa.z + fa.z; s[3] = xa.w + fa.w;
        s[4] = xb.x + fb.x; s[5] = xb.y + fb.y; s[6] = xb.z + fb.z; s[7] = xb.w + fb.w;
      }
      float sum = 0.f, ssq = 0.f;
#pragma unroll
      for (int i = 0; i < 8; ++i) { sum += s[i]; ssq += s[i] * s[i]; }
#pragma unroll
      for (int off = 32; off > 0; off >>= 1) {
        sum += __shfl_xor(sum, off);
        ssq += __shfl_xor(ssq, off);
      }
      const float mean = sum * (1.0f / 512.0f);
      const float var = ssq * (1.0f / 512.0f) - mean * mean;
      const float rstd = rsqrtf(fmaxf(var, 0.0f) + 1e-5f);
      float4 w0 = *(const float4*)(a.ln2w + c0);
      float4 w1 = *(const float4*)(a.ln2w + c0 + 4);
      float4 g0 = *(const float4*)(a.ln2b + c0);
      float4 g1 = *(const float4*)(a.ln2b + c0 + 4);
      const float wf[8] = {w0.x, w0.y, w0.z, w0.w, w1.x, w1.y, w1.z, w1.w};
      const float gf8[8] = {g0.x, g0.y, g0.z, g0.w, g1.x, g1.y, g1.z, g1.w};
      float o[8];
#pragma unroll
      for (int i = 0; i < 8; ++i) o[i] = (s[i] - mean) * rstd * wf[i] + gf8[i];
      *(float4*)(a.out + base + c0) = (float4){o[0], o[1], o[2], o[3]};
      *(float4*)(a.out + base + c0 + 4) = (float4){o[4], o[5], o[6], o[7]};
    }
  }
}

// ---------------------------------------------------------------------------
extern "C" void kernel_launch(void* const* d_in, const int* in_sizes, int n_in,
                              void* d_out, int out_size, void* d_ws, size_t ws_size,
                              hipStream_t stream) {
  const size_t MB = 1024 * 1024;
  char* wsb = (char*)d_ws;

  MegaArgs a;
  a.x     = (const float*)d_in[0];
  a.Wq    = (const float*)d_in[1];
  a.bq    = (const float*)d_in[2];
  a.Wk    = (const float*)d_in[3];
  a.bk    = (const float*)d_in[4];
  a.Wv    = (const float*)d_in[5];
  a.bv    = (const float*)d_in[6];
  a.theta = (const float*)d_in[7];
  a.gateA = (const float*)d_in[8];
  a.Wo    = (const float*)d_in[9];
  a.bo    = (const float*)d_in[10];
  a.ln1w  = (const float*)d_in[11];
  a.ln1b  = (const float*)d_in[12];
  a.W1    = (const float*)d_in[13];
  a.b1    = (const float*)d_in[14];
  a.W2    = (const float*)d_in[15];
  a.b2    = (const float*)d_in[16];
  a.phi   = (const float*)d_in[17];
  a.gateF = (const float*)d_in[18];
  a.ln2w  = (const float*)d_in[19];
  a.ln2b  = (const float*)d_in[20];
  a.out   = (float*)d_out;

  a.x_bf   = (__hip_bfloat16*)(wsb + 0 * MB);              // 4 MB
  a.Wq_bf  = (__hip_bfloat16*)(wsb + 4 * MB);              // 0.5 MB
  a.Wo_bf  = (__hip_bfloat16*)(wsb + 4 * MB + 512 * 1024); // 0.5 MB
  a.W2_bf  = (__hip_bfloat16*)(wsb + 5 * MB);              // 2 MB
  a.mix_bf = (__hip_bfloat16*)(wsb + 8 * MB);              // 4 MB
  a.attn   = (float*)(wsb + 12 * MB);                      // 8 MB
  a.x1     = (float*)(wsb + 20 * MB);                      // 8 MB
  a.hq_bf  = (__hip_bfloat16*)(wsb + 28 * MB);             // 16 MB
  a.Fb     = (float*)(wsb + 44 * MB);                      // 8 MB
  // conditional (gate != 1) buffers
  a.Qb     = (float*)(wsb + 52 * MB);                      // 8 MB
  a.Wk_bf  = (__hip_bfloat16*)(wsb + 60 * MB);
  a.Wv_bf  = (__hip_bfloat16*)(wsb + 60 * MB + 512 * 1024);
  a.Kb     = (float*)(wsb + 61 * MB);                      // 8 MB
  a.Vb     = (float*)(wsb + 69 * MB);                      // 8 MB
  a.hc_bf  = (__hip_bfloat16*)(wsb + 77 * MB);             // 16 MB
  a.Fc     = (float*)(wsb + 93 * MB);                      // 8 MB
  a.bar_cnt8 = (unsigned*)(wsb + 102 * MB);                // 8 x 128B lines
  a.bar_gcnt = (unsigned*)(wsb + 102 * MB + 1024);
  a.bar_gen  = (unsigned*)(wsb + 102 * MB + 1152);

  // zero barrier state (ws is re-poisoned 0xAA before every timed call)
  hipMemsetAsync(wsb + 102 * MB, 0, 4096, stream);
  mega<<<dim3(256), dim3(256), 0, stream>>>(a);
}

// Round 11
// 154.970 us; speedup vs baseline: 3.2068x; 1.4405x over previous
//
#include <hip/hip_runtime.h>
#include <hip/hip_bf16.h>

// Shapes fixed by the problem:
// B=4, S=1024, D=512, H=64, DK=8, FF=2048, NQ=8. Mtok = B*S = 4096.
// R10 verdict: persistent mega-kernel barriers cost ~17us each vs ~3us per
// graph-replay dispatch boundary -> reverted to the R6 multi-dispatch
// structure (162us), with ring-3 GEMM staging (prefetch depth 2) on top.

typedef short short8 __attribute__((ext_vector_type(8)));
typedef float floatx4 __attribute__((ext_vector_type(4)));

__device__ __forceinline__ unsigned short f2bf_bits(float f) {
  __hip_bfloat16 h = __float2bfloat16(f);
  return *reinterpret_cast<unsigned short*>(&h);
}
__device__ __forceinline__ float bfbits2f(unsigned short u) {
  union { unsigned int u; float f; } c;
  c.u = (unsigned int)u << 16;
  return c.f;
}

#define GLOBAL_LOAD_LDS16(g, l)                                               \
  __builtin_amdgcn_global_load_lds(                                           \
      (const __attribute__((address_space(1))) void*)(g),                     \
      (__attribute__((address_space(3))) void*)(l), 16, 0, 0)

// Compiler does NOT model global_load_lds's LDS write as aliasing later LDS
// reads (round-3 NaN). Explicit waits, memory clobber pins ordering.
#define WAIT_VMCNT0()   asm volatile("s_waitcnt vmcnt(0)" ::: "memory")
#define WAIT_VMCNT16()  asm volatile("s_waitcnt vmcnt(16)" ::: "memory")
#define WAIT_VMCNT32()  asm volatile("s_waitcnt vmcnt(32)" ::: "memory")
#define WAIT_LGKM0()    asm volatile("s_waitcnt lgkmcnt(0)" ::: "memory")

// ---------------------------------------------------------------------------
// Single-wave GEMM core, ring-3 staging: acc(64x64) += A @ W^T over K.
// 4x4 of 16x16x32 MFMA, BK=64. Three 16KB tile buffers; steady state keeps
// 2 tiles (32 loads) in flight and waits vmcnt(32) for the current tile
// only — prefetch depth 2 hides the ~500cyc LLC latency of cross-XCD
// operand reads (R6's depth-1 dbuf hid only ~250cyc). Single wave, only
// ~2 blocks/CU (grid-limited): latency must be hidden by ILP.
// XOR chunk swizzle: phys 16B chunk p of row r holds logical chunk
// p ^ (r&7) -> conflict-free ds_read_b128. sh = 24576 bf16 (48 KB).
// ---------------------------------------------------------------------------
__device__ __forceinline__ void gemm_core(
    const __hip_bfloat16* __restrict__ A,
    const __hip_bfloat16* __restrict__ W,
    int K, long m0, long n0, int lane,
    __hip_bfloat16* sh, floatx4 acc[4][4])
{
  const int srow = lane >> 3;
  const int gchunk = (lane & 7) ^ srow;
  const int frow = lane & 15;
  const int fk = lane >> 4;

  auto stage = [&](int kt, __hip_bfloat16* buf) {
#pragma unroll
    for (int ib = 0; ib < 8; ++ib) {
      const int row = ib * 8 + srow;
      GLOBAL_LOAD_LDS16(A + (m0 + row) * K + kt + gchunk * 8, buf + ib * 512);
      GLOBAL_LOAD_LDS16(W + (n0 + row) * K + kt + gchunk * 8, buf + 4096 + ib * 512);
    }
  };

  const int ntiles = K >> 6;            // >= 8 for all our shapes
  WAIT_LGKM0();                         // prior LDS reads retired
  stage(0, sh);
  if (ntiles > 1) stage(64, sh + 8192);
  if (ntiles > 2) stage(128, sh + 16384);

  for (int t = 0; t < ntiles; ++t) {
    __hip_bfloat16* buf = sh + (t % 3) * 8192;
    const int ahead = (ntiles - 1 - t) < 2 ? (ntiles - 1 - t) : 2;
    if (ahead == 2) { WAIT_VMCNT32(); }
    else if (ahead == 1) { WAIT_VMCNT16(); }
    else { WAIT_VMCNT0(); }

    short8 af[2][4], bf[2][4];
#pragma unroll
    for (int ks = 0; ks < 2; ++ks)
#pragma unroll
      for (int i = 0; i < 4; ++i) {
        const int ar = i * 16 + frow;
        af[ks][i] = *(const short8*)(buf + ar * 64 + (((ks * 4 + fk) ^ (ar & 7)) << 3));
        bf[ks][i] = *(const short8*)(buf + 4096 + ar * 64 + (((ks * 4 + fk) ^ (ar & 7)) << 3));
      }
    WAIT_LGKM0();                       // frags in VGPR before buf reuse
    if (t + 3 < ntiles) stage((t + 3) << 6, buf);
#pragma unroll
    for (int ks = 0; ks < 2; ++ks)
#pragma unroll
      for (int i = 0; i < 4; ++i)
#pragma unroll
        for (int j = 0; j < 4; ++j)
          acc[i][j] = __builtin_amdgcn_mfma_f32_16x16x32_bf16(
              af[ks][i], bf[ks][j], acc[i][j], 0, 0, 0);
  }
}

// ---------------------------------------------------------------------------
// QKV launch: grid (64, 8, 3). z=0: Q = x@Wq^T+bq with fused quantum
// epilogue -> mix_bf (bf16); if *gateA != 1 also writes Qb fp32.
// z=1/2: conditional K/V projections (early-exit when *gateA == 1).
// ---------------------------------------------------------------------------
__global__ __launch_bounds__(64) void gemm_qkv(
    const __hip_bfloat16* __restrict__ x_bf,
    const __hip_bfloat16* __restrict__ Wq,
    const __hip_bfloat16* __restrict__ Wk,
    const __hip_bfloat16* __restrict__ Wv,
    const float* __restrict__ bq, const float* __restrict__ bk,
    const float* __restrict__ bvv,
    __hip_bfloat16* __restrict__ mix,
    float* __restrict__ Qb, float* __restrict__ Kb, float* __restrict__ Vb,
    const float* __restrict__ theta, const float* __restrict__ gateA)
{
  const int z = blockIdx.z;
  const float g = *gateA;
  if (z > 0 && g == 1.0f) return;
  const __hip_bfloat16* W = (z == 0) ? Wq : (z == 1) ? Wk : Wv;
  const float* bias = (z == 0) ? bq : (z == 1) ? bk : bvv;
  float* Cf = (z == 0) ? Qb : (z == 1) ? Kb : Vb;

  __shared__ __align__(16) __hip_bfloat16 sh[24576];   // 48 KB ring
  const int lane = threadIdx.x;
  const long m0 = (long)blockIdx.x * 64;
  const long n0 = (long)blockIdx.y * 64;
  floatx4 acc[4][4];
#pragma unroll
  for (int i = 0; i < 4; ++i)
#pragma unroll
    for (int j = 0; j < 4; ++j) acc[i][j] = (floatx4){0.f, 0.f, 0.f, 0.f};

  gemm_core(x_bf, W, 512, m0, n0, lane, sh, acc);

  // D layout: row=(lane>>4)*4+reg, col=lane&15 (verified m89/m91)
  const int col_l = lane & 15;
  const int row_l = (lane >> 4) << 2;

  if (z > 0 || g != 1.0f) {
#pragma unroll
    for (int j = 0; j < 4; ++j) {
      const long col = n0 + j * 16 + col_l;
      const float bv = bias[col];
#pragma unroll
      for (int i = 0; i < 4; ++i)
#pragma unroll
        for (int r = 0; r < 4; ++r)
          Cf[(m0 + i * 16 + row_l + r) * 512 + col] = acc[i][j][r] + bv;
    }
  }
  if (z == 0) {
    // quantum epilogue: LDS-transpose acc(+bias), then per 8-wide head
    // group o[0]=c1..c7, o[j>=1]=c0..cj with c=cos(q+theta). Single wave:
    // DS pipe in-order; lgkm fences pin ordering/completion.
    float* shf = (float*)sh;   // 64x64 fp32 = 16 KB
    WAIT_LGKM0();
#pragma unroll
    for (int j = 0; j < 4; ++j) {
      const long col = n0 + j * 16 + col_l;
      const float bv = bias[col];
#pragma unroll
      for (int i = 0; i < 4; ++i)
#pragma unroll
        for (int r = 0; r < 4; ++r)
          shf[(i * 16 + row_l + r) * 64 + j * 16 + col_l] = acc[i][j][r] + bv;
    }
    WAIT_LGKM0();
    float th[8];
#pragma unroll
    for (int i = 0; i < 8; ++i) th[i] = theta[i];
#pragma unroll
    for (int t = 0; t < 8; ++t) {
      const int gidx = t * 64 + lane;
      const int row = gidx >> 3;
      const int hh = gidx & 7;
      const float* src = shf + row * 64 + hh * 8;
      float c[8];
#pragma unroll
      for (int i = 0; i < 8; ++i) c[i] = __cosf(src[i] + th[i]);
      float o[8];
      float p = c[1];
#pragma unroll
      for (int i = 2; i < 8; ++i) p *= c[i];
      o[0] = p;
      float cp = c[0];
#pragma unroll
      for (int i = 1; i < 8; ++i) { cp *= c[i]; o[i] = cp; }
      union { unsigned short u16[8]; uint4 v; } pk;
#pragma unroll
      for (int i = 0; i < 8; ++i) pk.u16[i] = f2bf_bits(o[i]);
      *(uint4*)(mix + (m0 + row) * 512 + n0 + hh * 8) = pk.v;
    }
  }
}

// ---------------------------------------------------------------------------
// Plain GEMM: C = A @ W^T + bias (fp32 out). grid (M/64, N/64).
// ---------------------------------------------------------------------------
__global__ __launch_bounds__(64) void gemm_plain(
    const __hip_bfloat16* __restrict__ A,
    const __hip_bfloat16* __restrict__ W,
    const float* __restrict__ bias, float* __restrict__ C, int N, int K)
{
  __shared__ __align__(16) __hip_bfloat16 sh[24576];
  const int lane = threadIdx.x;
  const long m0 = (long)blockIdx.x * 64;
  const long n0 = (long)blockIdx.y * 64;
  floatx4 acc[4][4];
#pragma unroll
  for (int i = 0; i < 4; ++i)
#pragma unroll
    for (int j = 0; j < 4; ++j) acc[i][j] = (floatx4){0.f, 0.f, 0.f, 0.f};
  gemm_core(A, W, K, m0, n0, lane, sh, acc);
  const int col_l = lane & 15;
  const int row_l = (lane >> 4) << 2;
#pragma unroll
  for (int j = 0; j < 4; ++j) {
    const long col = n0 + j * 16 + col_l;
    const float bv = bias[col];
#pragma unroll
    for (int i = 0; i < 4; ++i)
#pragma unroll
      for (int r = 0; r < 4; ++r)
        C[(m0 + i * 16 + row_l + r) * N + col] = acc[i][j][r] + bv;
  }
}

// ---------------------------------------------------------------------------
// FFN-out launch: grid (64, 8, 2). z=0: Fb = hq@W2^T+b2. z=1 (cond
// gateF!=1): Fc = hc@W2^T+b2.
// ---------------------------------------------------------------------------
__global__ __launch_bounds__(64) void gemm_ffnout(
    const __hip_bfloat16* __restrict__ hq,
    const __hip_bfloat16* __restrict__ hc,
    const __hip_bfloat16* __restrict__ W2, const float* __restrict__ b2,
    float* __restrict__ Fb, float* __restrict__ Fc,
    const float* __restrict__ gateF)
{
  const int z = blockIdx.z;
  if (z == 1 && *gateF == 1.0f) return;
  const __hip_bfloat16* A = z ? hc : hq;
  float* C = z ? Fc : Fb;
  __shared__ __align__(16) __hip_bfloat16 sh[24576];
  const int lane = threadIdx.x;
  const long m0 = (long)blockIdx.x * 64;
  const long n0 = (long)blockIdx.y * 64;
  floatx4 acc[4][4];
#pragma unroll
  for (int i = 0; i < 4; ++i)
#pragma unroll
    for (int j = 0; j < 4; ++j) acc[i][j] = (floatx4){0.f, 0.f, 0.f, 0.f};
  gemm_core(A, W2, 2048, m0, n0, lane, sh, acc);
  const int col_l = lane & 15;
  const int row_l = (lane >> 4) << 2;
#pragma unroll
  for (int j = 0; j < 4; ++j) {
    const long col = n0 + j * 16 + col_l;
    const float bv = b2[col];
#pragma unroll
    for (int i = 0; i < 4; ++i)
#pragma unroll
      for (int r = 0; r < 4; ++r)
        C[(m0 + i * 16 + row_l + r) * 512 + col] = acc[i][j][r] + bv;
  }
}

// ---------------------------------------------------------------------------
// input prep: fp32->bf16 for x, Wq, Wo, W2, W1 (contiguous); conditional
// Wk/Wv when *gateA != 1. One launch.
// ---------------------------------------------------------------------------
__device__ __forceinline__ void cvt_one(const float* s, __hip_bfloat16* d, int n,
                                        long tid, long stride) {
  const int n4 = n >> 2;
  for (long i = tid; i < n4; i += stride) {
    float4 v = ((const float4*)s)[i];
    ushort4 u;
    u.x = f2bf_bits(v.x); u.y = f2bf_bits(v.y);
    u.z = f2bf_bits(v.z); u.w = f2bf_bits(v.w);
    ((ushort4*)d)[i] = u;
  }
}

__global__ __launch_bounds__(256) void prep_inputs(
    const float* x, __hip_bfloat16* x_bf,
    const float* Wq, __hip_bfloat16* Wq_bf,
    const float* Wo, __hip_bfloat16* Wo_bf,
    const float* W2, __hip_bfloat16* W2_bf,
    const float* W1, __hip_bfloat16* W1_bf,
    const float* Wk, __hip_bfloat16* Wk_bf,
    const float* Wv, __hip_bfloat16* Wv_bf,
    const float* gateA)
{
  const long stride = (long)gridDim.x * blockDim.x;
  const long tid = (long)blockIdx.x * blockDim.x + threadIdx.x;
  cvt_one(x, x_bf, 4096 * 512, tid, stride);
  cvt_one(Wq, Wq_bf, 512 * 512, tid, stride);
  cvt_one(Wo, Wo_bf, 512 * 512, tid, stride);
  cvt_one(W2, W2_bf, 512 * 2048, tid, stride);
  cvt_one(W1, W1_bf, 2048 * 8, tid, stride);
  if (*gateA != 1.0f) {
    cvt_one(Wk, Wk_bf, 512 * 512, tid, stride);
    cvt_one(Wv, Wv_bf, 512 * 512, tid, stride);
  }
}

// ---------------------------------------------------------------------------
// [cond gateA!=1] classical softmax attention + blend into mix (bf16).
// One thread per (b,h,s), online softmax over 1024 keys, DK=8.
// ---------------------------------------------------------------------------
__global__ __launch_bounds__(256) void attn_blend(
    const float* __restrict__ Qb, const float* __restrict__ Kb,
    const float* __restrict__ Vb, __hip_bfloat16* __restrict__ mix,
    const float* __restrict__ gateA)
{
  const float g = *gateA;
  if (g == 1.0f) return;
  const int idx = blockIdx.x * blockDim.x + threadIdx.x;
  if (idx >= 4 * 64 * 1024) return;
  const int s = idx & 1023;
  const int h = (idx >> 10) & 63;
  const int b = idx >> 16;
  const long qoff = ((long)(b * 1024 + s)) * 512 + h * 8;
  float q[8];
#pragma unroll
  for (int i = 0; i < 8; ++i) q[i] = Qb[qoff + i] * 0.35355339059327373f;
  float m = -INFINITY, l = 0.0f, acc[8];
#pragma unroll
  for (int i = 0; i < 8; ++i) acc[i] = 0.0f;
  for (int t = 0; t < 1024; ++t) {
    const long koff = ((long)(b * 1024 + t)) * 512 + h * 8;
    const float* kr = Kb + koff;
    const float* vr = Vb + koff;
    float sc = 0.0f;
#pragma unroll
    for (int i = 0; i < 8; ++i) sc += q[i] * kr[i];
    float nm = fmaxf(m, sc);
    float corr = __expf(m - nm);
    float p = __expf(sc - nm);
    l = l * corr + p;
#pragma unroll
    for (int i = 0; i < 8; ++i) acc[i] = acc[i] * corr + p * vr[i];
    m = nm;
  }
  const float inv = 1.0f / l;
  union { unsigned short u16[8]; uint4 v; } pk;
  pk.v = *(const uint4*)(mix + qoff);
#pragma unroll
  for (int i = 0; i < 8; ++i) {
    float quant = bfbits2f(pk.u16[i]);
    pk.u16[i] = f2bf_bits(g * quant + (1.0f - g) * acc[i] * inv);
  }
  *(uint4*)(mix + qoff) = pk.v;
}

// ---------------------------------------------------------------------------
// LN1 + FFN-h fused. Block = 256 threads = 4 rows (wave-per-row LN, shfl
// only). Then all threads hold W1 (2048x8 bf16) slices in registers and
// compute hq = relu(qm @ W1^T + b1) -> bf16 (and hc from xs when gateF!=1).
// grid 1024.
// ---------------------------------------------------------------------------
__global__ __launch_bounds__(256) void lnffn2(
    const float* __restrict__ x, const float* __restrict__ attn,
    const float* __restrict__ lw, const float* __restrict__ lb,
    float* __restrict__ x1, const float* __restrict__ phi,
    const __hip_bfloat16* __restrict__ W1_bf, const float* __restrict__ b1,
    __hip_bfloat16* __restrict__ hq, __hip_bfloat16* __restrict__ hc,
    const float* __restrict__ gateF)
{
  const int tid = threadIdx.x;
  const int wv = tid >> 6, lane = tid & 63;
  const int row = blockIdx.x * 4 + wv;
  const long base = (long)row * 512;
  const int c0 = lane * 8;
  __shared__ float qrow[4][8];
  __shared__ float xsrow[4][8];

  float4 a0 = *(const float4*)(x + base + c0);
  float4 a1 = *(const float4*)(x + base + c0 + 4);
  float4 b0 = *(const float4*)(attn + base + c0);
  float4 b1v4 = *(const float4*)(attn + base + c0 + 4);
  float s[8] = {a0.x + b0.x, a0.y + b0.y, a0.z + b0.z, a0.w + b0.w,
                a1.x + b1v4.x, a1.y + b1v4.y, a1.z + b1v4.z, a1.w + b1v4.w};
  float sum = 0.f, ssq = 0.f;
#pragma unroll
  for (int i = 0; i < 8; ++i) { sum += s[i]; ssq += s[i] * s[i]; }
#pragma unroll
  for (int off = 32; off > 0; off >>= 1) {
    sum += __shfl_xor(sum, off);
    ssq += __shfl_xor(ssq, off);
  }
  const float mean = sum * (1.0f / 512.0f);
  const float var = ssq * (1.0f / 512.0f) - mean * mean;
  const float rstd = rsqrtf(fmaxf(var, 0.0f) + 1e-5f);
  float4 w0 = *(const float4*)(lw + c0);
  float4 w1 = *(const float4*)(lw + c0 + 4);
  float4 g0 = *(const float4*)(lb + c0);
  float4 g1 = *(const float4*)(lb + c0 + 4);
  float o[8];
  const float wf[8] = {w0.x, w0.y, w0.z, w0.w, w1.x, w1.y, w1.z, w1.w};
  const float gf8[8] = {g0.x, g0.y, g0.z, g0.w, g1.x, g1.y, g1.z, g1.w};
#pragma unroll
  for (int i = 0; i < 8; ++i) o[i] = (s[i] - mean) * rstd * wf[i] + gf8[i];
  *(float4*)(x1 + base + c0) = (float4){o[0], o[1], o[2], o[3]};
  *(float4*)(x1 + base + c0 + 4) = (float4){o[4], o[5], o[6], o[7]};
  if (lane == 0) {
#pragma unroll
    for (int i = 0; i < 8; ++i) {
      qrow[wv][i] = __cosf(o[i]) * __cosf(phi[i]);
      xsrow[wv][i] = o[i];
    }
  }
  __syncthreads();

  // FFN-h: thread owns outputs n = tid*8 .. tid*8+7 for all 4 rows.
  float w1f[8][8];
#pragma unroll
  for (int j = 0; j < 8; ++j) {
    uint4 wr = *(const uint4*)(W1_bf + (long)(tid * 8 + j) * 8);
    const unsigned short* pu = (const unsigned short*)&wr;
#pragma unroll
    for (int k = 0; k < 8; ++k) w1f[j][k] = bfbits2f(pu[k]);
  }
  float4 bb0 = *(const float4*)(b1 + tid * 8);
  float4 bb1 = *(const float4*)(b1 + tid * 8 + 4);
  const float b1v[8] = {bb0.x, bb0.y, bb0.z, bb0.w, bb1.x, bb1.y, bb1.z, bb1.w};
  const float gv = *gateF;
#pragma unroll
  for (int r = 0; r < 4; ++r) {
    const long rowr = (long)blockIdx.x * 4 + r;
    float qm[8];
#pragma unroll
    for (int k = 0; k < 8; ++k) qm[k] = qrow[r][k];
    union { unsigned short u16[8]; uint4 v; } pk;
#pragma unroll
    for (int j = 0; j < 8; ++j) {
      float acc = b1v[j];
#pragma unroll
      for (int k = 0; k < 8; ++k) acc += qm[k] * w1f[j][k];
      pk.u16[j] = f2bf_bits(fmaxf(acc, 0.0f));
    }
    *(uint4*)(hq + rowr * 2048 + tid * 8) = pk.v;
    if (gv != 1.0f) {
      float xs[8];
#pragma unroll
      for (int k = 0; k < 8; ++k) xs[k] = xsrow[r][k];
#pragma unroll
      for (int j = 0; j < 8; ++j) {
        float acc = b1v[j];
#pragma unroll
        for (int k = 0; k < 8; ++k) acc += xs[k] * w1f[j][k];
        pk.u16[j] = f2bf_bits(fmaxf(acc, 0.0f));
      }
      *(uint4*)(hc + rowr * 2048 + tid * 8) = pk.v;
    }
  }
}

// ---------------------------------------------------------------------------
// Final LN: out = LN(x1 + mix(Fb, Fc; gateF)). Wave-per-row, 4 rows/block,
// no barriers. grid 1024.
// ---------------------------------------------------------------------------
__global__ __launch_bounds__(256) void add_ln3(
    const float* __restrict__ x1, const float* __restrict__ Fb,
    const float* __restrict__ Fc, const float* __restrict__ gateF,
    const float* __restrict__ lw, const float* __restrict__ lb,
    float* __restrict__ out)
{
  const int tid = threadIdx.x;
  const int wv = tid >> 6, lane = tid & 63;
  const int row = blockIdx.x * 4 + wv;
  const long base = (long)row * 512;
  const int c0 = lane * 8;
  float4 a0 = *(const float4*)(x1 + base + c0);
  float4 a1 = *(const float4*)(x1 + base + c0 + 4);
  float4 f0 = *(const float4*)(Fb + base + c0);
  float4 f1 = *(const float4*)(Fb + base + c0 + 4);
  float s[8];
  const float gv = *gateF;
  if (gv != 1.0f) {
    float4 c0v = *(const float4*)(Fc + base + c0);
    float4 c1v = *(const float4*)(Fc + base + c0 + 4);
    const float om = 1.0f - gv;
    s[0] = a0.x + gv * f0.x + om * c0v.x; s[1] = a0.y + gv * f0.y + om * c0v.y;
    s[2] = a0.z + gv * f0.z + om * c0v.z; s[3] = a0.w + gv * f0.w + om * c0v.w;
    s[4] = a1.x + gv * f1.x + om * c1v.x; s[5] = a1.y + gv * f1.y + om * c1v.y;
    s[6] = a1.z + gv * f1.z + om * c1v.z; s[7] = a1.w + gv * f1.w + om * c1v.w;
  } else {
    s[0] = a0.x + f0.x; s[1] = a0.y + f0.y; s[2] = a0.z + f0.z; s[3] = a0.w + f0.w;
    s[4] = a1.x + f1.x; s[5] = a1.y + f1.y; s[6] = a1.z + f1.z; s[7] = a1.w + f1.w;
  }
  float sum = 0.f, ssq = 0.f;
#pragma unroll
  for (int i = 0; i < 8; ++i) { sum += s[i]; ssq += s[i] * s[i]; }
#pragma unroll
  for (int off = 32; off > 0; off >>= 1) {
    sum += __shfl_xor(sum, off);
    ssq += __shfl_xor(ssq, off);
  }
  const float mean = sum * (1.0f / 512.0f);
  const float var = ssq * (1.0f / 512.0f) - mean * mean;
  const float rstd = rsqrtf(fmaxf(var, 0.0f) + 1e-5f);
  float4 w0 = *(const float4*)(lw + c0);
  float4 w1 = *(const float4*)(lw + c0 + 4);
  float4 g0 = *(const float4*)(lb + c0);
  float4 g1 = *(const float4*)(lb + c0 + 4);
  const float wf[8] = {w0.x, w0.y, w0.z, w0.w, w1.x, w1.y, w1.z, w1.w};
  const float gf8[8] = {g0.x, g0.y, g0.z, g0.w, g1.x, g1.y, g1.z, g1.w};
  float o[8];
#pragma unroll
  for (int i = 0; i < 8; ++i) o[i] = (s[i] - mean) * rstd * wf[i] + gf8[i];
  *(float4*)(out + base + c0) = (float4){o[0], o[1], o[2], o[3]};
  *(float4*)(out + base + c0 + 4) = (float4){o[4], o[5], o[6], o[7]};
}

// ---------------------------------------------------------------------------
extern "C" void kernel_launch(void* const* d_in, const int* in_sizes, int n_in,
                              void* d_out, int out_size, void* d_ws, size_t ws_size,
                              hipStream_t stream) {
  const float* x     = (const float*)d_in[0];
  const float* Wq    = (const float*)d_in[1];
  const float* bq    = (const float*)d_in[2];
  const float* Wk    = (const float*)d_in[3];
  const float* bk    = (const float*)d_in[4];
  const float* Wv    = (const float*)d_in[5];
  const float* bv    = (const float*)d_in[6];
  const float* theta = (const float*)d_in[7];
  const float* gateA = (const float*)d_in[8];
  const float* Wo    = (const float*)d_in[9];
  const float* bo    = (const float*)d_in[10];
  const float* ln1w  = (const float*)d_in[11];
  const float* ln1b  = (const float*)d_in[12];
  const float* W1    = (const float*)d_in[13];
  const float* b1    = (const float*)d_in[14];
  const float* W2    = (const float*)d_in[15];
  const float* b2    = (const float*)d_in[16];
  const float* phi   = (const float*)d_in[17];
  const float* gateF = (const float*)d_in[18];
  const float* ln2w  = (const float*)d_in[19];
  const float* ln2b  = (const float*)d_in[20];
  float* out = (float*)d_out;

  const size_t MB = 1024 * 1024;
  char* wsb = (char*)d_ws;
  __hip_bfloat16* x_bf   = (__hip_bfloat16*)(wsb + 0 * MB);             // 4 MB
  __hip_bfloat16* Wq_bf  = (__hip_bfloat16*)(wsb + 4 * MB);             // 0.5 MB
  __hip_bfloat16* Wo_bf  = (__hip_bfloat16*)(wsb + 4 * MB + 512 * 1024);
  __hip_bfloat16* W2_bf  = (__hip_bfloat16*)(wsb + 5 * MB);             // 2 MB
  __hip_bfloat16* W1_bf  = (__hip_bfloat16*)(wsb + 7 * MB);             // 32 KB
  __hip_bfloat16* mix_bf = (__hip_bfloat16*)(wsb + 8 * MB);             // 4 MB
  float*          attn   = (float*)(wsb + 12 * MB);                     // 8 MB
  float*          x1     = (float*)(wsb + 20 * MB);                     // 8 MB
  __hip_bfloat16* hq_bf  = (__hip_bfloat16*)(wsb + 28 * MB);            // 16 MB
  float*          Fb     = (float*)(wsb + 44 * MB);                     // 8 MB
  // conditional (gate != 1) buffers
  float*          Qb     = (float*)(wsb + 52 * MB);                     // 8 MB
  __hip_bfloat16* Wk_bf  = (__hip_bfloat16*)(wsb + 60 * MB);
  __hip_bfloat16* Wv_bf  = (__hip_bfloat16*)(wsb + 60 * MB + 512 * 1024);
  float*          Kb2    = (float*)(wsb + 61 * MB);                     // 8 MB
  float*          Vb2    = (float*)(wsb + 69 * MB);                     // 8 MB
  __hip_bfloat16* hc_bf  = (__hip_bfloat16*)(wsb + 77 * MB);            // 16 MB
  float*          Fc     = (float*)(wsb + 93 * MB);                     // 8 MB

  // 1. input prep (all conversions)
  prep_inputs<<<1024, 256, 0, stream>>>(
      x, x_bf, Wq, Wq_bf, Wo, Wo_bf, W2, W2_bf, W1, W1_bf,
      Wk, Wk_bf, Wv, Wv_bf, gateA);
  // 2. QKV: z=0 Q+quantum -> mix_bf (+Qb cond); z=1/2 K/V (cond)
  gemm_qkv<<<dim3(64, 8, 3), 64, 0, stream>>>(
      x_bf, Wq_bf, Wk_bf, Wv_bf, bq, bk, bv,
      mix_bf, Qb, Kb2, Vb2, theta, gateA);
  // 3. [cond] classical attention + blend into mix_bf
  attn_blend<<<1024, 256, 0, stream>>>(Qb, Kb2, Vb2, mix_bf, gateA);
  // 4. attn = mix @ Wo^T + bo
  gemm_plain<<<dim3(64, 8), 64, 0, stream>>>(
      mix_bf, Wo_bf, bo, attn, 512, 512);
  // 5. x1 = LN(x+attn); hq (= relu(qm@W1^T+b1)) fused; hc cond
  lnffn2<<<1024, 256, 0, stream>>>(
      x, attn, ln1w, ln1b, x1, phi, W1_bf, b1, hq_bf, hc_bf, gateF);
  // 6. Fb = hq @ W2^T + b2 (z=0); Fc = hc @ W2^T + b2 (z=1, cond)
  gemm_ffnout<<<dim3(64, 8, 2), 64, 0, stream>>>(
      hq_bf, hc_bf, W2_bf, b2, Fb, Fc, gateF);
  // 7. out = LN(x1 + gF*Fb + (1-gF)*Fc)
  add_ln3<<<1024, 256, 0, stream>>>(x1, Fb, Fc, gateF, ln2w, ln2b, out);
}

// Round 12
// 153.938 us; speedup vs baseline: 3.2283x; 1.0067x over previous
//
#include <hip/hip_runtime.h>
#include <hip/hip_bf16.h>

// Shapes fixed by the problem:
// B=4, S=1024, D=512, H=64, DK=8, FF=2048, NQ=8. Mtok = B*S = 4096.
// R10 verdict: persistent mega-kernel barriers cost ~17us each vs ~3us per
// graph-replay dispatch boundary -> R6 multi-dispatch structure + ring-3
// GEMM staging (R11, 155us). R12: bf16 intermediates (attn/Fb/Fc) to cut
// 16MB of fp32 round-trip traffic.

typedef short short8 __attribute__((ext_vector_type(8)));
typedef float floatx4 __attribute__((ext_vector_type(4)));

__device__ __forceinline__ unsigned short f2bf_bits(float f) {
  __hip_bfloat16 h = __float2bfloat16(f);
  return *reinterpret_cast<unsigned short*>(&h);
}
__device__ __forceinline__ float bfbits2f(unsigned short u) {
  union { unsigned int u; float f; } c;
  c.u = (unsigned int)u << 16;
  return c.f;
}

#define GLOBAL_LOAD_LDS16(g, l)                                               \
  __builtin_amdgcn_global_load_lds(                                           \
      (const __attribute__((address_space(1))) void*)(g),                     \
      (__attribute__((address_space(3))) void*)(l), 16, 0, 0)

// Compiler does NOT model global_load_lds's LDS write as aliasing later LDS
// reads (round-3 NaN). Explicit waits, memory clobber pins ordering.
#define WAIT_VMCNT0()   asm volatile("s_waitcnt vmcnt(0)" ::: "memory")
#define WAIT_VMCNT16()  asm volatile("s_waitcnt vmcnt(16)" ::: "memory")
#define WAIT_VMCNT32()  asm volatile("s_waitcnt vmcnt(32)" ::: "memory")
#define WAIT_LGKM0()    asm volatile("s_waitcnt lgkmcnt(0)" ::: "memory")

// ---------------------------------------------------------------------------
// Single-wave GEMM core, ring-3 staging: acc(64x64) += A @ W^T over K.
// 4x4 of 16x16x32 MFMA, BK=64. Three 16KB tile buffers; steady state keeps
// 2 tiles (32 loads) in flight and waits vmcnt(32) for the current tile
// only — prefetch depth 2 hides ~500cyc LLC latency of cross-XCD operand
// reads. Single wave, ~2 blocks/CU (grid-limited): latency hidden by ILP.
// XOR chunk swizzle: phys 16B chunk p of row r holds logical chunk
// p ^ (r&7) -> conflict-free ds_read_b128. sh = 24576 bf16 (48 KB).
// ---------------------------------------------------------------------------
__device__ __forceinline__ void gemm_core(
    const __hip_bfloat16* __restrict__ A,
    const __hip_bfloat16* __restrict__ W,
    int K, long m0, long n0, int lane,
    __hip_bfloat16* sh, floatx4 acc[4][4])
{
  const int srow = lane >> 3;
  const int gchunk = (lane & 7) ^ srow;
  const int frow = lane & 15;
  const int fk = lane >> 4;

  auto stage = [&](int kt, __hip_bfloat16* buf) {
#pragma unroll
    for (int ib = 0; ib < 8; ++ib) {
      const int row = ib * 8 + srow;
      GLOBAL_LOAD_LDS16(A + (m0 + row) * K + kt + gchunk * 8, buf + ib * 512);
      GLOBAL_LOAD_LDS16(W + (n0 + row) * K + kt + gchunk * 8, buf + 4096 + ib * 512);
    }
  };

  const int ntiles = K >> 6;            // >= 8 for all our shapes
  WAIT_LGKM0();                         // prior LDS reads retired
  stage(0, sh);
  if (ntiles > 1) stage(64, sh + 8192);
  if (ntiles > 2) stage(128, sh + 16384);

  for (int t = 0; t < ntiles; ++t) {
    __hip_bfloat16* buf = sh + (t % 3) * 8192;
    const int ahead = (ntiles - 1 - t) < 2 ? (ntiles - 1 - t) : 2;
    if (ahead == 2) { WAIT_VMCNT32(); }
    else if (ahead == 1) { WAIT_VMCNT16(); }
    else { WAIT_VMCNT0(); }

    short8 af[2][4], bf[2][4];
#pragma unroll
    for (int ks = 0; ks < 2; ++ks)
#pragma unroll
      for (int i = 0; i < 4; ++i) {
        const int ar = i * 16 + frow;
        af[ks][i] = *(const short8*)(buf + ar * 64 + (((ks * 4 + fk) ^ (ar & 7)) << 3));
        bf[ks][i] = *(const short8*)(buf + 4096 + ar * 64 + (((ks * 4 + fk) ^ (ar & 7)) << 3));
      }
    WAIT_LGKM0();                       // frags in VGPR before buf reuse
    if (t + 3 < ntiles) stage((t + 3) << 6, buf);
#pragma unroll
    for (int ks = 0; ks < 2; ++ks)
#pragma unroll
      for (int i = 0; i < 4; ++i)
#pragma unroll
        for (int j = 0; j < 4; ++j)
          acc[i][j] = __builtin_amdgcn_mfma_f32_16x16x32_bf16(
              af[ks][i], bf[ks][j], acc[i][j], 0, 0, 0);
  }
}

// fp32 store epilogue, N=512. D layout: row=(lane>>4)*4+reg, col=lane&15.
__device__ __forceinline__ void store_f32(
    floatx4 acc[4][4], float* __restrict__ C, const float* __restrict__ bias,
    long m0, long n0, int lane)
{
  const int col_l = lane & 15;
  const int row_l = (lane >> 4) << 2;
#pragma unroll
  for (int j = 0; j < 4; ++j) {
    const long col = n0 + j * 16 + col_l;
    const float bv = bias[col];
#pragma unroll
    for (int i = 0; i < 4; ++i)
#pragma unroll
      for (int r = 0; r < 4; ++r)
        C[(m0 + i * 16 + row_l + r) * 512 + col] = acc[i][j][r] + bv;
  }
}

// bf16 store epilogue (R12: halves intermediate store traffic).
__device__ __forceinline__ void store_bf16(
    floatx4 acc[4][4], __hip_bfloat16* __restrict__ C,
    const float* __restrict__ bias, long m0, long n0, int lane)
{
  const int col_l = lane & 15;
  const int row_l = (lane >> 4) << 2;
#pragma unroll
  for (int j = 0; j < 4; ++j) {
    const long col = n0 + j * 16 + col_l;
    const float bv = bias[col];
#pragma unroll
    for (int i = 0; i < 4; ++i)
#pragma unroll
      for (int r = 0; r < 4; ++r)
        C[(m0 + i * 16 + row_l + r) * 512 + col] =
            __float2bfloat16(acc[i][j][r] + bv);
  }
}

// ---------------------------------------------------------------------------
// QKV launch: grid (64, 8, 3). z=0: Q = x@Wq^T+bq with fused quantum
// epilogue -> mix_bf (bf16); if *gateA != 1 also writes Qb fp32.
// z=1/2: conditional K/V projections (early-exit when *gateA == 1).
// ---------------------------------------------------------------------------
__global__ __launch_bounds__(64) void gemm_qkv(
    const __hip_bfloat16* __restrict__ x_bf,
    const __hip_bfloat16* __restrict__ Wq,
    const __hip_bfloat16* __restrict__ Wk,
    const __hip_bfloat16* __restrict__ Wv,
    const float* __restrict__ bq, const float* __restrict__ bk,
    const float* __restrict__ bvv,
    __hip_bfloat16* __restrict__ mix,
    float* __restrict__ Qb, float* __restrict__ Kb, float* __restrict__ Vb,
    const float* __restrict__ theta, const float* __restrict__ gateA)
{
  const int z = blockIdx.z;
  const float g = *gateA;
  if (z > 0 && g == 1.0f) return;
  const __hip_bfloat16* W = (z == 0) ? Wq : (z == 1) ? Wk : Wv;
  const float* bias = (z == 0) ? bq : (z == 1) ? bk : bvv;
  float* Cf = (z == 0) ? Qb : (z == 1) ? Kb : Vb;

  __shared__ __align__(16) __hip_bfloat16 sh[24576];   // 48 KB ring
  const int lane = threadIdx.x;
  const long m0 = (long)blockIdx.x * 64;
  const long n0 = (long)blockIdx.y * 64;
  floatx4 acc[4][4];
#pragma unroll
  for (int i = 0; i < 4; ++i)
#pragma unroll
    for (int j = 0; j < 4; ++j) acc[i][j] = (floatx4){0.f, 0.f, 0.f, 0.f};

  gemm_core(x_bf, W, 512, m0, n0, lane, sh, acc);

  const int col_l = lane & 15;
  const int row_l = (lane >> 4) << 2;

  if (z > 0 || g != 1.0f) store_f32(acc, Cf, bias, m0, n0, lane);
  if (z == 0) {
    // quantum epilogue: LDS-transpose acc(+bias), then per 8-wide head
    // group o[0]=c1..c7, o[j>=1]=c0..cj with c=cos(q+theta). Single wave:
    // DS pipe in-order; lgkm fences pin ordering/completion.
    float* shf = (float*)sh;   // 64x64 fp32 = 16 KB
    WAIT_LGKM0();
#pragma unroll
    for (int j = 0; j < 4; ++j) {
      const long col = n0 + j * 16 + col_l;
      const float bv = bias[col];
#pragma unroll
      for (int i = 0; i < 4; ++i)
#pragma unroll
        for (int r = 0; r < 4; ++r)
          shf[(i * 16 + row_l + r) * 64 + j * 16 + col_l] = acc[i][j][r] + bv;
    }
    WAIT_LGKM0();
    float th[8];
#pragma unroll
    for (int i = 0; i < 8; ++i) th[i] = theta[i];
#pragma unroll
    for (int t = 0; t < 8; ++t) {
      const int gidx = t * 64 + lane;
      const int row = gidx >> 3;
      const int hh = gidx & 7;
      const float* src = shf + row * 64 + hh * 8;
      float c[8];
#pragma unroll
      for (int i = 0; i < 8; ++i) c[i] = __cosf(src[i] + th[i]);
      float o[8];
      float p = c[1];
#pragma unroll
      for (int i = 2; i < 8; ++i) p *= c[i];
      o[0] = p;
      float cp = c[0];
#pragma unroll
      for (int i = 1; i < 8; ++i) { cp *= c[i]; o[i] = cp; }
      union { unsigned short u16[8]; uint4 v; } pk;
#pragma unroll
      for (int i = 0; i < 8; ++i) pk.u16[i] = f2bf_bits(o[i]);
      *(uint4*)(mix + (m0 + row) * 512 + n0 + hh * 8) = pk.v;
    }
  }
}

// ---------------------------------------------------------------------------
// Wo GEMM: attn_bf = (mix @ Wo^T + bo) as bf16. grid (64, 8).
// ---------------------------------------------------------------------------
__global__ __launch_bounds__(64) void gemm_wo(
    const __hip_bfloat16* __restrict__ A,
    const __hip_bfloat16* __restrict__ W,
    const float* __restrict__ bias, __hip_bfloat16* __restrict__ C, int K)
{
  __shared__ __align__(16) __hip_bfloat16 sh[24576];
  const int lane = threadIdx.x;
  const long m0 = (long)blockIdx.x * 64;
  const long n0 = (long)blockIdx.y * 64;
  floatx4 acc[4][4];
#pragma unroll
  for (int i = 0; i < 4; ++i)
#pragma unroll
    for (int j = 0; j < 4; ++j) acc[i][j] = (floatx4){0.f, 0.f, 0.f, 0.f};
  gemm_core(A, W, K, m0, n0, lane, sh, acc);
  store_bf16(acc, C, bias, m0, n0, lane);
}

// ---------------------------------------------------------------------------
// FFN-out launch: grid (64, 8, 2). z=0: Fb = hq@W2^T+b2 (bf16). z=1 (cond
// gateF!=1): Fc = hc@W2^T+b2 (bf16).
// ---------------------------------------------------------------------------
__global__ __launch_bounds__(64) void gemm_ffnout(
    const __hip_bfloat16* __restrict__ hq,
    const __hip_bfloat16* __restrict__ hc,
    const __hip_bfloat16* __restrict__ W2, const float* __restrict__ b2,
    __hip_bfloat16* __restrict__ Fb, __hip_bfloat16* __restrict__ Fc,
    const float* __restrict__ gateF)
{
  const int z = blockIdx.z;
  if (z == 1 && *gateF == 1.0f) return;
  const __hip_bfloat16* A = z ? hc : hq;
  __hip_bfloat16* C = z ? Fc : Fb;
  __shared__ __align__(16) __hip_bfloat16 sh[24576];
  const int lane = threadIdx.x;
  const long m0 = (long)blockIdx.x * 64;
  const long n0 = (long)blockIdx.y * 64;
  floatx4 acc[4][4];
#pragma unroll
  for (int i = 0; i < 4; ++i)
#pragma unroll
    for (int j = 0; j < 4; ++j) acc[i][j] = (floatx4){0.f, 0.f, 0.f, 0.f};
  gemm_core(A, W2, 2048, m0, n0, lane, sh, acc);
  store_bf16(acc, C, b2, m0, n0, lane);
}

// ---------------------------------------------------------------------------
// input prep: fp32->bf16 for x, Wq, Wo, W2, W1; conditional Wk/Wv.
// ---------------------------------------------------------------------------
__device__ __forceinline__ void cvt_one(const float* s, __hip_bfloat16* d, int n,
                                        long tid, long stride) {
  const int n4 = n >> 2;
  for (long i = tid; i < n4; i += stride) {
    float4 v = ((const float4*)s)[i];
    ushort4 u;
    u.x = f2bf_bits(v.x); u.y = f2bf_bits(v.y);
    u.z = f2bf_bits(v.z); u.w = f2bf_bits(v.w);
    ((ushort4*)d)[i] = u;
  }
}

__global__ __launch_bounds__(256) void prep_inputs(
    const float* x, __hip_bfloat16* x_bf,
    const float* Wq, __hip_bfloat16* Wq_bf,
    const float* Wo, __hip_bfloat16* Wo_bf,
    const float* W2, __hip_bfloat16* W2_bf,
    const float* W1, __hip_bfloat16* W1_bf,
    const float* Wk, __hip_bfloat16* Wk_bf,
    const float* Wv, __hip_bfloat16* Wv_bf,
    const float* gateA)
{
  const long stride = (long)gridDim.x * blockDim.x;
  const long tid = (long)blockIdx.x * blockDim.x + threadIdx.x;
  cvt_one(x, x_bf, 4096 * 512, tid, stride);
  cvt_one(Wq, Wq_bf, 512 * 512, tid, stride);
  cvt_one(Wo, Wo_bf, 512 * 512, tid, stride);
  cvt_one(W2, W2_bf, 512 * 2048, tid, stride);
  cvt_one(W1, W1_bf, 2048 * 8, tid, stride);
  if (*gateA != 1.0f) {
    cvt_one(Wk, Wk_bf, 512 * 512, tid, stride);
    cvt_one(Wv, Wv_bf, 512 * 512, tid, stride);
  }
}

// ---------------------------------------------------------------------------
// [cond gateA!=1] classical softmax attention + blend into mix (bf16).
// ---------------------------------------------------------------------------
__global__ __launch_bounds__(256) void attn_blend(
    const float* __restrict__ Qb, const float* __restrict__ Kb,
    const float* __restrict__ Vb, __hip_bfloat16* __restrict__ mix,
    const float* __restrict__ gateA)
{
  const float g = *gateA;
  if (g == 1.0f) return;
  const int idx = blockIdx.x * blockDim.x + threadIdx.x;
  if (idx >= 4 * 64 * 1024) return;
  const int s = idx & 1023;
  const int h = (idx >> 10) & 63;
  const int b = idx >> 16;
  const long qoff = ((long)(b * 1024 + s)) * 512 + h * 8;
  float q[8];
#pragma unroll
  for (int i = 0; i < 8; ++i) q[i] = Qb[qoff + i] * 0.35355339059327373f;
  float m = -INFINITY, l = 0.0f, acc[8];
#pragma unroll
  for (int i = 0; i < 8; ++i) acc[i] = 0.0f;
  for (int t = 0; t < 1024; ++t) {
    const long koff = ((long)(b * 1024 + t)) * 512 + h * 8;
    const float* kr = Kb + koff;
    const float* vr = Vb + koff;
    float sc = 0.0f;
#pragma unroll
    for (int i = 0; i < 8; ++i) sc += q[i] * kr[i];
    float nm = fmaxf(m, sc);
    float corr = __expf(m - nm);
    float p = __expf(sc - nm);
    l = l * corr + p;
#pragma unroll
    for (int i = 0; i < 8; ++i) acc[i] = acc[i] * corr + p * vr[i];
    m = nm;
  }
  const float inv = 1.0f / l;
  union { unsigned short u16[8]; uint4 v; } pk;
  pk.v = *(const uint4*)(mix + qoff);
#pragma unroll
  for (int i = 0; i < 8; ++i) {
    float quant = bfbits2f(pk.u16[i]);
    pk.u16[i] = f2bf_bits(g * quant + (1.0f - g) * acc[i] * inv);
  }
  *(uint4*)(mix + qoff) = pk.v;
}

// ---------------------------------------------------------------------------
// LN1 + FFN-h fused. Block = 256 threads = 4 rows (wave-per-row LN, shfl
// only). attn read as bf16 (R12). Then all threads hold W1 slices in
// registers and compute hq = relu(qm @ W1^T + b1) -> bf16 (+hc cond).
// grid 1024.
// ---------------------------------------------------------------------------
__global__ __launch_bounds__(256) void lnffn2(
    const float* __restrict__ x, const __hip_bfloat16* __restrict__ attn,
    const float* __restrict__ lw, const float* __restrict__ lb,
    float* __restrict__ x1, const float* __restrict__ phi,
    const __hip_bfloat16* __restrict__ W1_bf, const float* __restrict__ b1,
    __hip_bfloat16* __restrict__ hq, __hip_bfloat16* __restrict__ hc,
    const float* __restrict__ gateF)
{
  const int tid = threadIdx.x;
  const int wv = tid >> 6, lane = tid & 63;
  const int row = blockIdx.x * 4 + wv;
  const long base = (long)row * 512;
  const int c0 = lane * 8;
  __shared__ float qrow[4][8];
  __shared__ float xsrow[4][8];

  float4 a0 = *(const float4*)(x + base + c0);
  float4 a1 = *(const float4*)(x + base + c0 + 4);
  union { unsigned short u16[8]; uint4 v; } at;
  at.v = *(const uint4*)(attn + base + c0);
  float s[8] = {a0.x + bfbits2f(at.u16[0]), a0.y + bfbits2f(at.u16[1]),
                a0.z + bfbits2f(at.u16[2]), a0.w + bfbits2f(at.u16[3]),
                a1.x + bfbits2f(at.u16[4]), a1.y + bfbits2f(at.u16[5]),
                a1.z + bfbits2f(at.u16[6]), a1.w + bfbits2f(at.u16[7])};
  float sum = 0.f, ssq = 0.f;
#pragma unroll
  for (int i = 0; i < 8; ++i) { sum += s[i]; ssq += s[i] * s[i]; }
#pragma unroll
  for (int off = 32; off > 0; off >>= 1) {
    sum += __shfl_xor(sum, off);
    ssq += __shfl_xor(ssq, off);
  }
  const float mean = sum * (1.0f / 512.0f);
  const float var = ssq * (1.0f / 512.0f) - mean * mean;
  const float rstd = rsqrtf(fmaxf(var, 0.0f) + 1e-5f);
  float4 w0 = *(const float4*)(lw + c0);
  float4 w1 = *(const float4*)(lw + c0 + 4);
  float4 g0 = *(const float4*)(lb + c0);
  float4 g1 = *(const float4*)(lb + c0 + 4);
  float o[8];
  const float wf[8] = {w0.x, w0.y, w0.z, w0.w, w1.x, w1.y, w1.z, w1.w};
  const float gf8[8] = {g0.x, g0.y, g0.z, g0.w, g1.x, g1.y, g1.z, g1.w};
#pragma unroll
  for (int i = 0; i < 8; ++i) o[i] = (s[i] - mean) * rstd * wf[i] + gf8[i];
  *(float4*)(x1 + base + c0) = (float4){o[0], o[1], o[2], o[3]};
  *(float4*)(x1 + base + c0 + 4) = (float4){o[4], o[5], o[6], o[7]};
  if (lane == 0) {
#pragma unroll
    for (int i = 0; i < 8; ++i) {
      qrow[wv][i] = __cosf(o[i]) * __cosf(phi[i]);
      xsrow[wv][i] = o[i];
    }
  }
  __syncthreads();

  // FFN-h: thread owns outputs n = tid*8 .. tid*8+7 for all 4 rows.
  float w1f[8][8];
#pragma unroll
  for (int j = 0; j < 8; ++j) {
    uint4 wr = *(const uint4*)(W1_bf + (long)(tid * 8 + j) * 8);
    const unsigned short* pu = (const unsigned short*)&wr;
#pragma unroll
    for (int k = 0; k < 8; ++k) w1f[j][k] = bfbits2f(pu[k]);
  }
  float4 bb0 = *(const float4*)(b1 + tid * 8);
  float4 bb1 = *(const float4*)(b1 + tid * 8 + 4);
  const float b1v[8] = {bb0.x, bb0.y, bb0.z, bb0.w, bb1.x, bb1.y, bb1.z, bb1.w};
  const float gv = *gateF;
#pragma unroll
  for (int r = 0; r < 4; ++r) {
    const long rowr = (long)blockIdx.x * 4 + r;
    float qm[8];
#pragma unroll
    for (int k = 0; k < 8; ++k) qm[k] = qrow[r][k];
    union { unsigned short u16[8]; uint4 v; } pk;
#pragma unroll
    for (int j = 0; j < 8; ++j) {
      float acc = b1v[j];
#pragma unroll
      for (int k = 0; k < 8; ++k) acc += qm[k] * w1f[j][k];
      pk.u16[j] = f2bf_bits(fmaxf(acc, 0.0f));
    }
    *(uint4*)(hq + rowr * 2048 + tid * 8) = pk.v;
    if (gv != 1.0f) {
      float xs[8];
#pragma unroll
      for (int k = 0; k < 8; ++k) xs[k] = xsrow[r][k];
#pragma unroll
      for (int j = 0; j < 8; ++j) {
        float acc = b1v[j];
#pragma unroll
        for (int k = 0; k < 8; ++k) acc += xs[k] * w1f[j][k];
        pk.u16[j] = f2bf_bits(fmaxf(acc, 0.0f));
      }
      *(uint4*)(hc + rowr * 2048 + tid * 8) = pk.v;
    }
  }
}

// ---------------------------------------------------------------------------
// Final LN: out = LN(x1 + mix(Fb, Fc; gateF)), Fb/Fc bf16 (R12).
// Wave-per-row, 4 rows/block, no barriers. grid 1024.
// ---------------------------------------------------------------------------
__global__ __launch_bounds__(256) void add_ln3(
    const float* __restrict__ x1, const __hip_bfloat16* __restrict__ Fb,
    const __hip_bfloat16* __restrict__ Fc, const float* __restrict__ gateF,
    const float* __restrict__ lw, const float* __restrict__ lb,
    float* __restrict__ out)
{
  const int tid = threadIdx.x;
  const int wv = tid >> 6, lane = tid & 63;
  const int row = blockIdx.x * 4 + wv;
  const long base = (long)row * 512;
  const int c0 = lane * 8;
  float4 a0 = *(const float4*)(x1 + base + c0);
  float4 a1 = *(const float4*)(x1 + base + c0 + 4);
  union { unsigned short u16[8]; uint4 v; } fb;
  fb.v = *(const uint4*)(Fb + base + c0);
  const float xa[8] = {a0.x, a0.y, a0.z, a0.w, a1.x, a1.y, a1.z, a1.w};
  float s[8];
  const float gv = *gateF;
  if (gv != 1.0f) {
    union { unsigned short u16[8]; uint4 v; } fc;
    fc.v = *(const uint4*)(Fc + base + c0);
    const float om = 1.0f - gv;
#pragma unroll
    for (int i = 0; i < 8; ++i)
      s[i] = xa[i] + gv * bfbits2f(fb.u16[i]) + om * bfbits2f(fc.u16[i]);
  } else {
#pragma unroll
    for (int i = 0; i < 8; ++i) s[i] = xa[i] + bfbits2f(fb.u16[i]);
  }
  float sum = 0.f, ssq = 0.f;
#pragma unroll
  for (int i = 0; i < 8; ++i) { sum += s[i]; ssq += s[i] * s[i]; }
#pragma unroll
  for (int off = 32; off > 0; off >>= 1) {
    sum += __shfl_xor(sum, off);
    ssq += __shfl_xor(ssq, off);
  }
  const float mean = sum * (1.0f / 512.0f);
  const float var = ssq * (1.0f / 512.0f) - mean * mean;
  const float rstd = rsqrtf(fmaxf(var, 0.0f) + 1e-5f);
  float4 w0 = *(const float4*)(lw + c0);
  float4 w1 = *(const float4*)(lw + c0 + 4);
  float4 g0 = *(const float4*)(lb + c0);
  float4 g1 = *(const float4*)(lb + c0 + 4);
  const float wf[8] = {w0.x, w0.y, w0.z, w0.w, w1.x, w1.y, w1.z, w1.w};
  const float gf8[8] = {g0.x, g0.y, g0.z, g0.w, g1.x, g1.y, g1.z, g1.w};
  float o[8];
#pragma unroll
  for (int i = 0; i < 8; ++i) o[i] = (s[i] - mean) * rstd * wf[i] + gf8[i];
  *(float4*)(out + base + c0) = (float4){o[0], o[1], o[2], o[3]};
  *(float4*)(out + base + c0 + 4) = (float4){o[4], o[5], o[6], o[7]};
}

// ---------------------------------------------------------------------------
extern "C" void kernel_launch(void* const* d_in, const int* in_sizes, int n_in,
                              void* d_out, int out_size, void* d_ws, size_t ws_size,
                              hipStream_t stream) {
  const float* x     = (const float*)d_in[0];
  const float* Wq    = (const float*)d_in[1];
  const float* bq    = (const float*)d_in[2];
  const float* Wk    = (const float*)d_in[3];
  const float* bk    = (const float*)d_in[4];
  const float* Wv    = (const float*)d_in[5];
  const float* bv    = (const float*)d_in[6];
  const float* theta = (const float*)d_in[7];
  const float* gateA = (const float*)d_in[8];
  const float* Wo    = (const float*)d_in[9];
  const float* bo    = (const float*)d_in[10];
  const float* ln1w  = (const float*)d_in[11];
  const float* ln1b  = (const float*)d_in[12];
  const float* W1    = (const float*)d_in[13];
  const float* b1    = (const float*)d_in[14];
  const float* W2    = (const float*)d_in[15];
  const float* b2    = (const float*)d_in[16];
  const float* phi   = (const float*)d_in[17];
  const float* gateF = (const float*)d_in[18];
  const float* ln2w  = (const float*)d_in[19];
  const float* ln2b  = (const float*)d_in[20];
  float* out = (float*)d_out;

  const size_t MB = 1024 * 1024;
  char* wsb = (char*)d_ws;
  __hip_bfloat16* x_bf    = (__hip_bfloat16*)(wsb + 0 * MB);            // 4 MB
  __hip_bfloat16* Wq_bf   = (__hip_bfloat16*)(wsb + 4 * MB);            // 0.5 MB
  __hip_bfloat16* Wo_bf   = (__hip_bfloat16*)(wsb + 4 * MB + 512 * 1024);
  __hip_bfloat16* W2_bf   = (__hip_bfloat16*)(wsb + 5 * MB);            // 2 MB
  __hip_bfloat16* W1_bf   = (__hip_bfloat16*)(wsb + 7 * MB);            // 32 KB
  __hip_bfloat16* mix_bf  = (__hip_bfloat16*)(wsb + 8 * MB);            // 4 MB
  __hip_bfloat16* attn_bf = (__hip_bfloat16*)(wsb + 12 * MB);           // 4 MB
  float*          x1      = (float*)(wsb + 16 * MB);                    // 8 MB
  __hip_bfloat16* hq_bf   = (__hip_bfloat16*)(wsb + 24 * MB);           // 16 MB
  __hip_bfloat16* Fb_bf   = (__hip_bfloat16*)(wsb + 40 * MB);           // 4 MB
  // conditional (gate != 1) buffers
  float*          Qb      = (float*)(wsb + 52 * MB);                    // 8 MB
  __hip_bfloat16* Wk_bf   = (__hip_bfloat16*)(wsb + 60 * MB);
  __hip_bfloat16* Wv_bf   = (__hip_bfloat16*)(wsb + 60 * MB + 512 * 1024);
  float*          Kb2     = (float*)(wsb + 61 * MB);                    // 8 MB
  float*          Vb2     = (float*)(wsb + 69 * MB);                    // 8 MB
  __hip_bfloat16* hc_bf   = (__hip_bfloat16*)(wsb + 77 * MB);           // 16 MB
  __hip_bfloat16* Fc_bf   = (__hip_bfloat16*)(wsb + 93 * MB);           // 4 MB

  // 1. input prep (all conversions)
  prep_inputs<<<1024, 256, 0, stream>>>(
      x, x_bf, Wq, Wq_bf, Wo, Wo_bf, W2, W2_bf, W1, W1_bf,
      Wk, Wk_bf, Wv, Wv_bf, gateA);
  // 2. QKV: z=0 Q+quantum -> mix_bf (+Qb cond); z=1/2 K/V (cond)
  gemm_qkv<<<dim3(64, 8, 3), 64, 0, stream>>>(
      x_bf, Wq_bf, Wk_bf, Wv_bf, bq, bk, bv,
      mix_bf, Qb, Kb2, Vb2, theta, gateA);
  // 3. [cond] classical attention + blend into mix_bf
  attn_blend<<<1024, 256, 0, stream>>>(Qb, Kb2, Vb2, mix_bf, gateA);
  // 4. attn_bf = (mix @ Wo^T + bo) bf16
  gemm_wo<<<dim3(64, 8), 64, 0, stream>>>(mix_bf, Wo_bf, bo, attn_bf, 512);
  // 5. x1 = LN(x+attn); hq (= relu(qm@W1^T+b1)) fused; hc cond
  lnffn2<<<1024, 256, 0, stream>>>(
      x, attn_bf, ln1w, ln1b, x1, phi, W1_bf, b1, hq_bf, hc_bf, gateF);
  // 6. Fb = hq @ W2^T + b2 (z=0); Fc = hc @ W2^T + b2 (z=1, cond), bf16
  gemm_ffnout<<<dim3(64, 8, 2), 64, 0, stream>>>(
      hq_bf, hc_bf, W2_bf, b2, Fb_bf, Fc_bf, gateF);
  // 7. out = LN(x1 + gF*Fb + (1-gF)*Fc)
  add_ln3<<<1024, 256, 0, stream>>>(x1, Fb_bf, Fc_bf, gateF, ln2w, ln2b, out);
}